// Round 3
// baseline (271.575 us; speedup 1.0000x reference)
//
#include <hip/hip_runtime.h>
#include <math.h>

// Problem constants
constexpr int Bn = 8, Cn = 128, Ln = 4096;

// Workspace layout (float offsets). z (transposed) / s / xbca / Sprev stored as bf16.
constexpr size_t OFF_O1   = 0;          // o1; later o3 (aliased)
constexpr size_t OFF_O2   = 4194304;
constexpr size_t OFF_S    = 8388608;    // bf16: 8*4096*32 ushort
constexpr size_t OFF_Z    = 9437184;    // bf16 zT[dir][p=64][b=8][l=4096]
constexpr size_t OFF_WT   = 11534336;   // bf16 WT[dir][n=272][k=32]
constexpr size_t OFF_XBCA = 13631488;   // bf16: 2 dirs x 6,291,456 ushort
constexpr size_t OFF_DTS  = 26214400;
constexpr size_t OFF_CUM  = 26279936;
constexpr size_t OFF_T    = 26345472;   // 2 dirs x 2,097,152 floats
constexpr size_t OFF_SPREV= 30539776;   // bf16: 2 dirs x 2,097,152 ushort
constexpr size_t OFF_S2A  = 34734080;
constexpr size_t OFF_S2B  = 35782656;
constexpr size_t OFF_BN   = 36831232;
constexpr size_t OFF_O3   = 0;

constexpr long XSTRIDE_H = 6291456;   // ushort elements per dir
constexpr long TSTRIDE = 2097152;     // element stride per dir (f32 for T, u16 for Sprev)

typedef __attribute__((ext_vector_type(8))) short short8;
typedef __attribute__((ext_vector_type(4))) float f32x4;
typedef __attribute__((ext_vector_type(4))) unsigned short us4;

__device__ __forceinline__ float siluf(float v) { return v / (1.0f + expf(-v)); }

__device__ __forceinline__ unsigned short tobf(float f) {
  unsigned int u = __float_as_uint(f);
  u += 0x7FFFu + ((u >> 16) & 1u);     // RNE
  return (unsigned short)(u >> 16);
}

__device__ __forceinline__ float frombf(unsigned short u) {
  return __uint_as_float(((unsigned int)u) << 16);
}

// 8 consecutive bf16 from LDS via 4 dword reads (>=4B-aligned offsets)
__device__ __forceinline__ short8 ldfrag(const unsigned short* p) {
  union { unsigned int u[4]; short8 s; } cv;
  cv.u[0] = *(const unsigned int*)(p);
  cv.u[1] = *(const unsigned int*)(p + 2);
  cv.u[2] = *(const unsigned int*)(p + 4);
  cv.u[3] = *(const unsigned int*)(p + 6);
  return cv.s;
}

// K1: o1[b,c,l] = sum_k x[b,k,l]*w[k,c] + bias[c] — MFMA bf16, K=128.
__global__ __launch_bounds__(256) void k_lin1(const float* __restrict__ x,
                                              const float* __restrict__ w,
                                              const float* __restrict__ bias,
                                              float* __restrict__ o1) {
  __shared__ unsigned short wT[64][140];
  __shared__ unsigned short xT[64][140];
  int b = blockIdx.y, l0 = blockIdx.x * 64, cb = blockIdx.z * 64;
  int tid = threadIdx.x, lane = tid & 63, mt = tid >> 6;
  int q = lane >> 4, i = lane & 15;
  int c4 = (tid & 15) * 4, k0 = tid >> 4;
#pragma unroll
  for (int s = 0; s < 8; ++s) {
    int k = k0 + s * 16;
    float4 wv = *(const float4*)&w[k * 128 + cb + c4];
    wT[c4 + 0][k] = tobf(wv.x); wT[c4 + 1][k] = tobf(wv.y);
    wT[c4 + 2][k] = tobf(wv.z); wT[c4 + 3][k] = tobf(wv.w);
    float4 xv = *(const float4*)&x[((long)b * 128 + k) * 4096 + l0 + c4];
    xT[c4 + 0][k] = tobf(xv.x); xT[c4 + 1][k] = tobf(xv.y);
    xT[c4 + 2][k] = tobf(xv.z); xT[c4 + 3][k] = tobf(xv.w);
  }
  __syncthreads();
  short8 af[4];
#pragma unroll
  for (int kk = 0; kk < 4; ++kk)
    af[kk] = ldfrag(&wT[mt * 16 + i][q * 8 + 32 * kk]);
  float bv[4];
#pragma unroll
  for (int r2 = 0; r2 < 4; ++r2) bv[r2] = bias[cb + 16 * mt + q * 4 + r2];
#pragma unroll
  for (int nt = 0; nt < 4; ++nt) {
    f32x4 d = {0.f, 0.f, 0.f, 0.f};
#pragma unroll
    for (int kk = 0; kk < 4; ++kk) {
      short8 bfr = ldfrag(&xT[nt * 16 + i][q * 8 + 32 * kk]);
      d = __builtin_amdgcn_mfma_f32_16x16x32_bf16(af[kk], bfr, d, 0, 0, 0);
    }
#pragma unroll
    for (int r2 = 0; r2 < 4; ++r2) {
      int c = 16 * mt + q * 4 + r2;
      o1[((long)b * 128 + cb + c) * 4096 + l0 + nt * 16 + i] = d[r2] + bv[r2];
    }
  }
}

// K2: depthwise 3x3 SAME + bias + silu. 4x4 patch per thread from LDS plane.
__global__ void k_dw(const float* __restrict__ o1, const float* __restrict__ wgt,
                     const float* __restrict__ bias, float* __restrict__ o2) {
  __shared__ float p[4096];
  int bc = blockIdx.x, c = bc & 127, tid = threadIdx.x;
  const float* src = o1 + (long)bc * 4096;
#pragma unroll
  for (int s4 = 0; s4 < 4; ++s4) {
    int off = s4 * 1024 + tid * 4;
    *(float4*)&p[off] = *(const float4*)&src[off];
  }
  float wr[9];
#pragma unroll
  for (int j = 0; j < 9; ++j) wr[j] = wgt[c * 9 + j];
  float bv = bias[c];
  __syncthreads();
  int wg = tid & 15, hs = tid >> 4;
  int w0 = wg * 4, h0 = hs * 4;
  float in[6][6];
#pragma unroll
  for (int ri = 0; ri < 6; ++ri) {
    int h = h0 - 1 + ri;
    if (h < 0 || h > 63) {
#pragma unroll
      for (int ci = 0; ci < 6; ++ci) in[ri][ci] = 0.f;
    } else {
      float4 cc = *(float4*)&p[h * 64 + w0];
      in[ri][1] = cc.x; in[ri][2] = cc.y; in[ri][3] = cc.z; in[ri][4] = cc.w;
      in[ri][0] = (w0 > 0) ? p[h * 64 + w0 - 1] : 0.f;
      in[ri][5] = (w0 < 60) ? p[h * 64 + w0 + 4] : 0.f;
    }
  }
#pragma unroll
  for (int r = 0; r < 4; ++r) {
    float oc[4];
#pragma unroll
    for (int q = 0; q < 4; ++q) {
      float acc = bv;
#pragma unroll
      for (int dh = 0; dh < 3; ++dh)
#pragma unroll
        for (int dq = 0; dq < 3; ++dq)
          acc += in[r + dh][q + dq] * wr[dh * 3 + dq];
      oc[q] = siluf(acc);
    }
    *(float4*)&o2[(long)bc * 4096 + (h0 + r) * 64 + w0] =
        make_float4(oc[0], oc[1], oc[2], oc[3]);
  }
}

// K3: s[b,l,d] = sum_c o2[b,c,l]*w[c,d] (d<32). Output bf16. Also folds prepW
// (one-time Win -> bf16 transpose) into blocks (x<2, y==0).
__global__ void k_fcin(const float* __restrict__ o2, const float* __restrict__ w,
                       unsigned short* __restrict__ sb,
                       const float* __restrict__ Win, unsigned short* __restrict__ WT) {
  __shared__ float xt[128][64];
  __shared__ float wt[128][32];
  int b = blockIdx.y, l0 = blockIdx.x * 64;
  int tid = threadIdx.x;
  int f4 = (tid & 15) * 4, r0 = tid >> 4;
#pragma unroll
  for (int st = 0; st < 8; ++st) {
    int r = r0 + st * 16;
    *(float4*)&xt[r][f4] = *(const float4*)&o2[((long)b * 128 + r) * 4096 + l0 + f4];
  }
  int f4w = (tid & 7) * 4, rw = tid >> 3;
#pragma unroll
  for (int st = 0; st < 4; ++st) {
    int r = rw + st * 32;
    *(float4*)&wt[r][f4w] = *(const float4*)&w[r * 32 + f4w];
  }
  __syncthreads();
  int tx = tid & 15, ty = tid >> 4;
  int c0 = tx * 4, d0 = ty * 2;
  float acc[2][4] = {};
  for (int k = 0; k < 128; ++k) {
    float4 xv = *(float4*)&xt[k][c0];
    float2 wv = *(float2*)&wt[k][d0];
    float xa[4] = {xv.x, xv.y, xv.z, xv.w};
#pragma unroll
    for (int q = 0; q < 4; ++q) {
      acc[0][q] += wv.x * xa[q];
      acc[1][q] += wv.y * xa[q];
    }
  }
#pragma unroll
  for (int q = 0; q < 4; ++q) {
    long ob = ((long)b * 4096 + l0 + c0 + q) * 32 + d0;
    unsigned int pk = (unsigned int)tobf(acc[0][q]) |
                      ((unsigned int)tobf(acc[1][q]) << 16);
    *(unsigned int*)&sb[ob] = pk;
  }
  // ---- folded prepW: WT[dir][n(272 padded)][k(32)], zeros n>=257 ----
  if (blockIdx.y == 0 && blockIdx.x < 2) {
    int dir = blockIdx.x;
    for (int idx = tid; idx < 272 * 32; idx += 256) {
      int n = idx >> 5, kk = idx & 31;
      float v = (n < 257) ? Win[dir * 32 * 257 + kk * 257 + n] : 0.f;
      WT[dir * 8704 + idx] = tobf(v);
    }
  }
}

// K4: in_proj (MFMA bf16, K=32) + causal conv1d + silu + dt softplus + cum
//     + fused chunk summary T[p][n] = sum_s f_s*X_s[p]*B_s[n] (MFMA bf16).
__global__ __launch_bounds__(256) void k_inprojconv(
    const unsigned short* __restrict__ sb, const unsigned short* __restrict__ WT,
    const float* __restrict__ conv_w, const float* __restrict__ conv_b,
    const float* __restrict__ dt_bias, const float* __restrict__ A_log,
    unsigned short* __restrict__ zT, unsigned short* __restrict__ xbca,
    float* __restrict__ dts, float* __restrict__ cum, float* __restrict__ Tg) {
  __shared__ unsigned short xbcT[192][82];   // [channel][t], pitch 82: conflict-free
  __shared__ float fXf[64][68];              // fp32 silu(X) for T's A-operand
  __shared__ float dtL[64];                  // raw dt MFMA outputs
  __shared__ float dtsS[64], cumSS[64], fL[64];
  int dir = blockIdx.z, b = blockIdx.y, l0 = blockIdx.x * 64;
  int tid = threadIdx.x, lane = tid & 63, mt = tid >> 6;
  int q = lane >> 4, i = lane & 15;
  long rowbase = (long)b * 4096 + l0;
  const unsigned short* W = WT + (long)dir * 8704;
  const short8 zfrag = {0, 0, 0, 0, 0, 0, 0, 0};

  if (mt == 0) {
    // ---- z columns (n 0..63) + dt column, l0-aligned rows ----
    short8 afr[4];
#pragma unroll
    for (int rt = 0; rt < 4; ++rt) {
      int l = l0 + 16 * rt + i;
      int lsrc = dir ? (4095 - l) : l;
      afr[rt] = *(const short8*)&sb[((long)b * 4096 + lsrc) * 32 + q * 8];
    }
#pragma unroll
    for (int ct = 0; ct < 4; ++ct) {
      int n = 16 * ct + i;
      short8 bfr = *(const short8*)&W[n * 32 + q * 8];
      unsigned short* zrow = zT + (((long)dir * 64 + n) * 8 + b) * 4096 + l0 + q * 4;
#pragma unroll
      for (int rt = 0; rt < 4; ++rt) {
        f32x4 d = {0.f, 0.f, 0.f, 0.f};
        d = __builtin_amdgcn_mfma_f32_16x16x32_bf16(afr[rt], bfr, d, 0, 0, 0);
        us4 pk;
        pk[0] = tobf(d[0]); pk[1] = tobf(d[1]);
        pk[2] = tobf(d[2]); pk[3] = tobf(d[3]);
        *(us4*)&zrow[16 * rt] = pk;
      }
    }
    {
      short8 bfr = *(const short8*)&W[(256 + i) * 32 + q * 8];
#pragma unroll
      for (int rt = 0; rt < 4; ++rt) {
        f32x4 d = {0.f, 0.f, 0.f, 0.f};
        d = __builtin_amdgcn_mfma_f32_16x16x32_bf16(afr[rt], bfr, d, 0, 0, 0);
        if (i == 0) {
#pragma unroll
          for (int r2 = 0; r2 < 4; ++r2) dtL[16 * rt + q * 4 + r2] = d[r2];
        }
      }
    }
  } else {
    // ---- xbc columns (n 64..255), rows with -3 conv halo ----
    short8 afr[5];
#pragma unroll
    for (int rt = 0; rt < 5; ++rt) {
      int l = l0 - 3 + 16 * rt + i;
      if (l >= 0 && l < 4096) {
        int lsrc = dir ? (4095 - l) : l;
        afr[rt] = *(const short8*)&sb[((long)b * 4096 + lsrc) * 32 + q * 8];
      } else {
        afr[rt] = zfrag;
      }
    }
#pragma unroll
    for (int cti = 0; cti < 4; ++cti) {
      int n = 16 * (mt * 4 + cti) + i;
      short8 bfr = *(const short8*)&W[n * 32 + q * 8];
      int cc = n - 64;
#pragma unroll
      for (int rt = 0; rt < 5; ++rt) {
        f32x4 d = {0.f, 0.f, 0.f, 0.f};
        d = __builtin_amdgcn_mfma_f32_16x16x32_bf16(afr[rt], bfr, d, 0, 0, 0);
        int rr0 = 16 * rt + q * 4;
        unsigned int p0 = (unsigned int)tobf(d[0]) | ((unsigned int)tobf(d[1]) << 16);
        unsigned int p1 = (unsigned int)tobf(d[2]) | ((unsigned int)tobf(d[3]) << 16);
        *(unsigned int*)&xbcT[cc][rr0] = p0;
        *(unsigned int*)&xbcT[cc][rr0 + 2] = p1;
      }
    }
  }
  __syncthreads();

  if (tid < 192) {
    int c = tid;
    float cw0 = conv_w[dir * 768 + c * 4 + 0];
    float cw1 = conv_w[dir * 768 + c * 4 + 1];
    float cw2 = conv_w[dir * 768 + c * 4 + 2];
    float cw3 = conv_w[dir * 768 + c * 4 + 3];
    float cb2 = conv_b[dir * 192 + c];
    unsigned short* xp = xbca + (long)dir * XSTRIDE_H;
    float win0 = 0.f, win1 = 0.f, win2 = 0.f, win3 = 0.f;
    for (int rp = 0; rp < 34; ++rp) {
      unsigned int pk = *(const unsigned int*)&xbcT[c][rp * 2];
      float a0 = frombf((unsigned short)(pk & 0xFFFFu));
      float a1 = frombf((unsigned short)(pk >> 16));
      int rr = rp * 2;
      win0 = win1; win1 = win2; win2 = win3; win3 = a0;
      if (rr >= 3 && rr <= 66) {
        float acc = cb2 + win0 * cw0 + win1 * cw1 + win2 * cw2 + win3 * cw3;
        float sv = siluf(acc);
        int t = rr - 3;
        xp[(rowbase + t) * 192 + c] = tobf(sv);
        if (c < 64) fXf[c][t] = sv;                        // fp32 X for T
        else if (c < 128) xbcT[c][t] = tobf(sv);           // bf16 B for T (trails reads by 3)
      }
      win0 = win1; win1 = win2; win2 = win3; win3 = a1;
      if (rr + 1 >= 3 && rr + 1 <= 66) {
        float acc = cb2 + win0 * cw0 + win1 * cw1 + win2 * cw2 + win3 * cw3;
        float sv = siluf(acc);
        int t = rr - 2;
        xp[(rowbase + t) * 192 + c] = tobf(sv);
        if (c < 64) fXf[c][t] = sv;
        else if (c < 128) xbcT[c][t] = tobf(sv);
      }
    }
  } else {
    int ln = tid - 192;
    float v = dtL[ln] + dt_bias[dir];
    float sp = (v > 20.f) ? v : log1pf(expf(v));
    dts[dir * 32768 + rowbase + ln] = sp;
    dtsS[ln] = sp;
    float cd = -expf(A_log[dir]) * sp;
#pragma unroll
    for (int off = 1; off < 64; off <<= 1) {
      float u = __shfl_up(cd, off);
      if (ln >= off) cd += u;
    }
    cum[dir * 32768 + rowbase + ln] = cd;
    cumSS[ln] = cd;
  }
  __syncthreads();

  if (tid < 64) fL[tid] = expf(cumSS[63] - cumSS[tid]) * dtsS[tid];
  __syncthreads();

  // scale phase: xbcT rows 0..63 <- tobf(fXf * fL)
  {
    int c = tid & 63, tb2 = (tid >> 6) * 16;
#pragma unroll
    for (int j = 0; j < 8; ++j) {
      int t = tb2 + 2 * j;
      float2 v = *(const float2*)&fXf[c][t];
      unsigned int pk = (unsigned int)tobf(v.x * fL[t]) |
                        ((unsigned int)tobf(v.y * fL[t + 1]) << 16);
      *(unsigned int*)&xbcT[c][t] = pk;
    }
  }
  __syncthreads();

  // MFMA-T: T[p][n] = sum_t fX[p][t] * B[n][t], K=64 (two K=32 MFMAs)
  {
    short8 a0 = ldfrag(&xbcT[mt * 16 + i][q * 8]);
    short8 a1 = ldfrag(&xbcT[mt * 16 + i][q * 8 + 32]);
    float* Tp = Tg + (long)dir * TSTRIDE + ((long)(b * 64 + blockIdx.x)) * 4096;
#pragma unroll
    for (int nt = 0; nt < 4; ++nt) {
      short8 b0 = ldfrag(&xbcT[64 + nt * 16 + i][q * 8]);
      short8 b1 = ldfrag(&xbcT[64 + nt * 16 + i][q * 8 + 32]);
      f32x4 d = {0.f, 0.f, 0.f, 0.f};
      d = __builtin_amdgcn_mfma_f32_16x16x32_bf16(a0, b0, d, 0, 0, 0);
      d = __builtin_amdgcn_mfma_f32_16x16x32_bf16(a1, b1, d, 0, 0, 0);
#pragma unroll
      for (int r2 = 0; r2 < 4; ++r2)
        Tp[(mt * 16 + q * 4 + r2) * 64 + nt * 16 + i] = d[r2];
    }
  }
}

// K7: inter-chunk state scan — pn-pairs, 16-deep prefetch, bf16 output.
__global__ void k_scan(const float* __restrict__ T, const float* __restrict__ cum,
                       unsigned short* __restrict__ Sprev) {
  __shared__ float E[64];
  int blk = blockIdx.x;            // 128 blocks
  int dirb = blk >> 3;             // dir*8 + b
  int dir = dirb >> 3, b = dirb & 7;
  int pn = (blk & 7) * 512 + threadIdx.x * 2;
  const float* cp = cum + dir * 32768 + b * 4096;
  if (threadIdx.x < 64) E[threadIdx.x] = expf(cp[threadIdx.x * 64 + 63]);
  __syncthreads();
  const float* Tp = T + (long)dir * TSTRIDE + (long)b * 262144 + pn;
  unsigned short* Sp = Sprev + (long)dir * TSTRIDE + (long)b * 262144 + pn;
  float s0 = 0.f, s1 = 0.f;
  float2 tb[16];
#pragma unroll
  for (int j = 0; j < 16; ++j) tb[j] = *(const float2*)&Tp[(long)j * 4096];
  for (int kc = 0; kc < 4; ++kc) {
    float2 tn[16];
    if (kc < 3) {
#pragma unroll
      for (int j = 0; j < 16; ++j)
        tn[j] = *(const float2*)&Tp[(long)(kc * 16 + 16 + j) * 4096];
    }
#pragma unroll
    for (int j = 0; j < 16; ++j) {
      int k = kc * 16 + j;
      unsigned int pk = (unsigned int)tobf(s0) | ((unsigned int)tobf(s1) << 16);
      *(unsigned int*)&Sp[(long)k * 4096] = pk;
      s0 = fmaf(E[k], s0, tb[j].x);
      s1 = fmaf(E[k], s1, tb[j].y);
    }
    if (kc < 3) {
#pragma unroll
      for (int j = 0; j < 16; ++j) tb[j] = tn[j];
    }
  }
}

// K8: per-chunk Y + gate + RMSNorm + out-proj — MFMA bf16, vectorized staging.
__global__ __launch_bounds__(256) void k_chunkYout(
    const unsigned short* __restrict__ xbca, const float* __restrict__ dts,
    const float* __restrict__ cum, const unsigned short* __restrict__ Sprev,
    const float* __restrict__ Dp, const unsigned short* __restrict__ zT,
    const float* __restrict__ normw, const float* __restrict__ Wout,
    float* __restrict__ s2a, float* __restrict__ s2b) {
  __shared__ unsigned short Cb[64][72];
  __shared__ unsigned short Bop[64][68];
  __shared__ unsigned short Gb[64][72];
  __shared__ unsigned short WnT[32][66];
  __shared__ float cumS[64];
  int dir = blockIdx.y;
  int bk = blockIdx.x, b = bk >> 6, k = bk & 63;
  int tid = threadIdx.x, lane = tid & 63, mt = tid >> 6;
  int q = lane >> 4, i = lane & 15;
  const unsigned short* xp = xbca + (long)dir * XSTRIDE_H;
  const float* dtp = dts + dir * 32768;
  const float* cp = cum + dir * 32768;
  const unsigned short* Sp = Sprev + (long)dir * TSTRIDE;
  long base = (long)b * 4096 + (long)k * 64;

  {
    int c4 = (tid & 15) * 4, r0 = tid >> 4;
#pragma unroll
    for (int s = 0; s < 4; ++s) {
      int r = r0 + s * 16;
      float dtv = dtp[base + r];
      const unsigned short* rowp = &xp[(base + r) * 192 + 64];
      us4 bv = *(const us4*)&rowp[c4];
      us4 cv = *(const us4*)&rowp[64 + c4];
      us4 bo;
#pragma unroll
      for (int j = 0; j < 4; ++j) bo[j] = tobf(frombf(bv[j]) * dtv);
      *(us4*)&Bop[r][c4] = bo;
      *(us4*)&Cb[r][c4] = cv;
    }
  }
  for (int idx = tid; idx < 2048; idx += 256) {
    int p = idx >> 5, d = idx & 31;
    WnT[d][p] = tobf(normw[dir * 64 + p] * Wout[(long)dir * 2048 + p * 32 + d]);
  }
  if (tid < 64) cumS[tid] = cp[base + tid];
  __syncthreads();

  short8 a0 = *(const short8*)&Cb[mt * 16 + i][q * 8];
  short8 a1 = *(const short8*)&Cb[mt * 16 + i][q * 8 + 32];

#pragma unroll
  for (int lt = 0; lt < 4; ++lt) {
    short8 b0 = ldfrag(&Bop[lt * 16 + i][q * 8]);
    short8 b1 = ldfrag(&Bop[lt * 16 + i][q * 8 + 32]);
    f32x4 d = {0.f, 0.f, 0.f, 0.f};
    d = __builtin_amdgcn_mfma_f32_16x16x32_bf16(a0, b0, d, 0, 0, 0);
    d = __builtin_amdgcn_mfma_f32_16x16x32_bf16(a1, b1, d, 0, 0, 0);
#pragma unroll
    for (int r2 = 0; r2 < 4; ++r2) {
      int t = mt * 16 + q * 4 + r2;
      int l = lt * 16 + i;
      float g = (l <= t) ? d[r2] * expf(cumS[t] - cumS[l]) : 0.f;
      Gb[t][l] = tobf(g);
    }
  }
  __syncthreads();

  {
    int c4 = (tid & 15) * 4, r0 = tid >> 4;
#pragma unroll
    for (int s = 0; s < 4; ++s) {
      int r = r0 + s * 16;
      us4 sv = *(const us4*)&Sp[(long)bk * 4096 + r * 64 + c4];
      *(us4*)&Bop[r][c4] = sv;
    }
  }
  __syncthreads();

  f32x4 dint[4];
#pragma unroll
  for (int lt = 0; lt < 4; ++lt) {
    short8 b0 = ldfrag(&Bop[lt * 16 + i][q * 8]);
    short8 b1 = ldfrag(&Bop[lt * 16 + i][q * 8 + 32]);
    f32x4 d = {0.f, 0.f, 0.f, 0.f};
    d = __builtin_amdgcn_mfma_f32_16x16x32_bf16(a0, b0, d, 0, 0, 0);
    d = __builtin_amdgcn_mfma_f32_16x16x32_bf16(a1, b1, d, 0, 0, 0);
    dint[lt] = d;
  }
  __syncthreads();

  // Repack X transposed into Bop: Bop[p][t] = X[row t][channel p]
#pragma unroll
  for (int j = 0; j < 8; ++j) {
    int s = mt * 16 + 2 * j;
    unsigned int pk = (unsigned int)xp[(base + s) * 192 + lane] |
                      ((unsigned int)xp[(base + s + 1) * 192 + lane] << 16);
    *(unsigned int*)&Bop[lane][s] = pk;
  }
  __syncthreads();

  short8 g0 = *(const short8*)&Gb[mt * 16 + i][q * 8];
  short8 g1 = *(const short8*)&Gb[mt * 16 + i][q * 8 + 32];
  float Dv = Dp[dir];
  float et4[4];
#pragma unroll
  for (int r2 = 0; r2 < 4; ++r2) et4[r2] = expf(cumS[mt * 16 + q * 4 + r2]);
  float yv[4][4];
  float rowss[4] = {0.f, 0.f, 0.f, 0.f};
#pragma unroll
  for (int lt = 0; lt < 4; ++lt) {
    short8 b0 = ldfrag(&Bop[lt * 16 + i][q * 8]);
    short8 b1 = ldfrag(&Bop[lt * 16 + i][q * 8 + 32]);
    f32x4 d = {0.f, 0.f, 0.f, 0.f};
    d = __builtin_amdgcn_mfma_f32_16x16x32_bf16(g0, b0, d, 0, 0, 0);
    d = __builtin_amdgcn_mfma_f32_16x16x32_bf16(g1, b1, d, 0, 0, 0);
    us4 zq = *(const us4*)&zT[(((long)dir * 64 + lt * 16 + i) * 8 + b) * 4096 +
                              (long)k * 64 + mt * 16 + q * 4];
    unsigned int xpk0 = *(const unsigned int*)&Bop[lt * 16 + i][mt * 16 + q * 4];
    unsigned int xpk1 = *(const unsigned int*)&Bop[lt * 16 + i][mt * 16 + q * 4 + 2];
    float xvr[4];
    xvr[0] = frombf((unsigned short)(xpk0 & 0xFFFFu));
    xvr[1] = frombf((unsigned short)(xpk0 >> 16));
    xvr[2] = frombf((unsigned short)(xpk1 & 0xFFFFu));
    xvr[3] = frombf((unsigned short)(xpk1 >> 16));
#pragma unroll
    for (int r2 = 0; r2 < 4; ++r2) {
      float y = d[r2] + et4[r2] * dint[lt][r2] + Dv * xvr[r2];
      float zv = frombf(zq[r2]);
      float v = y * siluf(zv);
      yv[lt][r2] = v;
      rowss[r2] += v * v;
    }
  }
#pragma unroll
  for (int m = 1; m < 16; m <<= 1) {
#pragma unroll
    for (int r2 = 0; r2 < 4; ++r2) rowss[r2] += __shfl_xor(rowss[r2], m);
  }
  float rscv[4];
#pragma unroll
  for (int r2 = 0; r2 < 4; ++r2)
    rscv[r2] = rsqrtf(rowss[r2] * (1.0f / 64.0f) + 1e-5f);
#pragma unroll
  for (int lt = 0; lt < 4; ++lt)
#pragma unroll
    for (int r2 = 0; r2 < 4; ++r2) {
      int t = mt * 16 + q * 4 + r2;
      int p = lt * 16 + i;
      Gb[t][p] = tobf(yv[lt][r2] * rscv[r2]);
    }
  __syncthreads();

  short8 y0 = *(const short8*)&Gb[mt * 16 + i][q * 8];
  short8 y1 = *(const short8*)&Gb[mt * 16 + i][q * 8 + 32];
  float* s2x = dir ? s2b : s2a;
#pragma unroll
  for (int dt = 0; dt < 2; ++dt) {
    short8 b0 = ldfrag(&WnT[dt * 16 + i][q * 8]);
    short8 b1 = ldfrag(&WnT[dt * 16 + i][q * 8 + 32]);
    f32x4 d = {0.f, 0.f, 0.f, 0.f};
    d = __builtin_amdgcn_mfma_f32_16x16x32_bf16(y0, b0, d, 0, 0, 0);
    d = __builtin_amdgcn_mfma_f32_16x16x32_bf16(y1, b1, d, 0, 0, 0);
#pragma unroll
    for (int r2 = 0; r2 < 4; ++r2) {
      int tl = mt * 16 + q * 4 + r2;
      int l = k * 64 + tl;
      int lout = dir ? (4095 - l) : l;
      int dd = dt * 16 + i;
      s2x[((long)b * 4096 + lout) * 32 + dd] = d[r2];
    }
  }
}

// K10: o3 = (s2a+s2b)@W — GEMM + fused BN partial sums (atomics).
__global__ void k_fcout(const float* __restrict__ s2a, const float* __restrict__ s2b,
                        const float* __restrict__ w, float* __restrict__ o3,
                        float* __restrict__ stats) {
  __shared__ float st[32][68];
  __shared__ float wt[32][64];
  int b = blockIdx.y, l0 = blockIdx.x * 64, cb = blockIdx.z * 64;
  int tid = threadIdx.x;
  {
    int d = tid & 31, l = tid >> 5;
    for (int si = 0; si < 8; ++si) {
      int ll = l + si * 8;
      long o = ((long)b * 4096 + l0 + ll) * 32 + d;
      st[d][ll] = s2a[o] + s2b[o];
    }
    int f4 = (tid & 15) * 4, r = tid >> 4;
    for (int si = 0; si < 2; ++si) {
      int rr = r + si * 16;
      *(float4*)&wt[rr][f4] = *(const float4*)&w[rr * 128 + cb + f4];
    }
  }
  __syncthreads();
  int tx = tid & 15, ty = tid >> 4;
  int c0 = tx * 4, t0 = ty * 4;
  float acc[4][4] = {};
  for (int k = 0; k < 32; ++k) {
    float4 xv = *(float4*)&st[k][c0];
    float4 wv = *(float4*)&wt[k][t0];
    float xa[4] = {xv.x, xv.y, xv.z, xv.w};
    float wa[4] = {wv.x, wv.y, wv.z, wv.w};
#pragma unroll
    for (int a = 0; a < 4; ++a)
#pragma unroll
      for (int q = 0; q < 4; ++q) acc[a][q] += wa[a] * xa[q];
  }
#pragma unroll
  for (int a = 0; a < 4; ++a)
    *(float4*)&o3[((long)b * 128 + cb + t0 + a) * 4096 + l0 + c0] =
        make_float4(acc[a][0], acc[a][1], acc[a][2], acc[a][3]);
  // ---- fused BN stats: per-channel sum/sumsq over this block's 64 l ----
  float ssum[4], sqq[4];
#pragma unroll
  for (int a = 0; a < 4; ++a) {
    ssum[a] = acc[a][0] + acc[a][1] + acc[a][2] + acc[a][3];
    sqq[a] = acc[a][0] * acc[a][0] + acc[a][1] * acc[a][1] +
             acc[a][2] * acc[a][2] + acc[a][3] * acc[a][3];
  }
#pragma unroll
  for (int m = 1; m < 16; m <<= 1) {
#pragma unroll
    for (int a = 0; a < 4; ++a) {
      ssum[a] += __shfl_xor(ssum[a], m);
      sqq[a] += __shfl_xor(sqq[a], m);
    }
  }
  if (tx == 0) {
#pragma unroll
    for (int a = 0; a < 4; ++a) {
      int ch = cb + t0 + a;
      atomicAdd(&stats[ch], ssum[a]);
      atomicAdd(&stats[128 + ch], sqq[a]);
    }
  }
}

// K12: BN + conv4 + sigmoid + gated residual — MFMA bf16 (BN folded in staging).
__global__ __launch_bounds__(256) void k_final(const float* __restrict__ o3,
                                               const float* __restrict__ stats,
                                               const float* __restrict__ bng,
                                               const float* __restrict__ bnb,
                                               const float* __restrict__ w,
                                               const float* __restrict__ bias,
                                               const float* __restrict__ x,
                                               float* __restrict__ out) {
  __shared__ unsigned short wT[64][140];
  __shared__ unsigned short aT[64][140];
  __shared__ float sc[128], sh[128];
  int b = blockIdx.y, l0 = blockIdx.x * 64, cb = blockIdx.z * 64;
  int tid = threadIdx.x, lane = tid & 63, mt = tid >> 6;
  int q = lane >> 4, i = lane & 15;
  if (tid < 128) {
    float mu = stats[tid] * (1.0f / 32768.0f);
    float var = stats[128 + tid] * (1.0f / 32768.0f) - mu * mu;
    float r = rsqrtf(var + 1e-5f);
    sc[tid] = r * bng[tid];
    sh[tid] = bnb[tid] - mu * r * bng[tid];
  }
  __syncthreads();
  int c4 = (tid & 15) * 4, k0 = tid >> 4;
#pragma unroll
  for (int s = 0; s < 8; ++s) {
    int k = k0 + s * 16;
    float4 wv = *(const float4*)&w[k * 128 + cb + c4];
    wT[c4 + 0][k] = tobf(wv.x); wT[c4 + 1][k] = tobf(wv.y);
    wT[c4 + 2][k] = tobf(wv.z); wT[c4 + 3][k] = tobf(wv.w);
    float4 av = *(const float4*)&o3[((long)b * 128 + k) * 4096 + l0 + c4];
    float scr = sc[k], shr = sh[k];
    aT[c4 + 0][k] = tobf(fmaf(av.x, scr, shr));
    aT[c4 + 1][k] = tobf(fmaf(av.y, scr, shr));
    aT[c4 + 2][k] = tobf(fmaf(av.z, scr, shr));
    aT[c4 + 3][k] = tobf(fmaf(av.w, scr, shr));
  }
  __syncthreads();
  short8 af[4];
#pragma unroll
  for (int kk = 0; kk < 4; ++kk)
    af[kk] = ldfrag(&wT[mt * 16 + i][q * 8 + 32 * kk]);
  float bv[4];
#pragma unroll
  for (int r2 = 0; r2 < 4; ++r2) bv[r2] = bias[cb + 16 * mt + q * 4 + r2];
#pragma unroll
  for (int nt = 0; nt < 4; ++nt) {
    f32x4 d = {0.f, 0.f, 0.f, 0.f};
#pragma unroll
    for (int kk = 0; kk < 4; ++kk) {
      short8 bfr = ldfrag(&aT[nt * 16 + i][q * 8 + 32 * kk]);
      d = __builtin_amdgcn_mfma_f32_16x16x32_bf16(af[kk], bfr, d, 0, 0, 0);
    }
#pragma unroll
    for (int r2 = 0; r2 < 4; ++r2) {
      int c = 16 * mt + q * 4 + r2;
      long xi = ((long)b * 128 + cb + c) * 4096 + l0 + nt * 16 + i;
      float g = 1.0f / (1.0f + expf(-(d[r2] + bv[r2])));
      out[xi] = x[xi] * (1.0f + g);
    }
  }
}

extern "C" void kernel_launch(void* const* d_in, const int* in_sizes, int n_in,
                              void* d_out, int out_size, void* d_ws, size_t ws_size,
                              hipStream_t stream) {
  const float* x          = (const float*)d_in[0];
  const float* lin1_w     = (const float*)d_in[1];
  const float* lin1_b     = (const float*)d_in[2];
  const float* dw_w       = (const float*)d_in[3];
  const float* dw_b       = (const float*)d_in[4];
  const float* fc_in_w    = (const float*)d_in[5];
  const float* mam_in_w   = (const float*)d_in[6];
  const float* mam_conv_w = (const float*)d_in[7];
  const float* mam_conv_b = (const float*)d_in[8];
  const float* mam_dt_bias= (const float*)d_in[9];
  const float* mam_A_log  = (const float*)d_in[10];
  const float* mam_D      = (const float*)d_in[11];
  const float* mam_norm_w = (const float*)d_in[12];
  const float* mam_out_w  = (const float*)d_in[13];
  const float* fc_out_w   = (const float*)d_in[14];
  const float* bn_g       = (const float*)d_in[15];
  const float* bn_b       = (const float*)d_in[16];
  const float* conv4_w    = (const float*)d_in[17];
  const float* conv4_b    = (const float*)d_in[18];
  float* out = (float*)d_out;
  float* ws  = (float*)d_ws;

  float* o1   = ws + OFF_O1;
  float* o2   = ws + OFF_O2;
  unsigned short* sbuf = (unsigned short*)(ws + OFF_S);
  unsigned short* zTb  = (unsigned short*)(ws + OFF_Z);
  unsigned short* WTb  = (unsigned short*)(ws + OFF_WT);
  unsigned short* xbca = (unsigned short*)(ws + OFF_XBCA);
  float* dts  = ws + OFF_DTS;
  float* cum  = ws + OFF_CUM;
  float* Tbuf = ws + OFF_T;
  unsigned short* Sprev = (unsigned short*)(ws + OFF_SPREV);
  float* s2a  = ws + OFF_S2A;
  float* s2b  = ws + OFF_S2B;
  float* bnst = ws + OFF_BN;
  float* o3   = ws + OFF_O3;

  hipMemsetAsync(bnst, 0, 256 * sizeof(float), stream);

  k_lin1<<<dim3(64, 8, 2), 256, 0, stream>>>(x, lin1_w, lin1_b, o1);
  k_dw<<<1024, 256, 0, stream>>>(o1, dw_w, dw_b, o2);
  k_fcin<<<dim3(64, 8), 256, 0, stream>>>(o2, fc_in_w, sbuf, mam_in_w, WTb);
  k_inprojconv<<<dim3(64, 8, 2), 256, 0, stream>>>(sbuf, WTb, mam_conv_w, mam_conv_b,
                                                   mam_dt_bias, mam_A_log,
                                                   zTb, xbca, dts, cum, Tbuf);
  k_scan<<<128, 256, 0, stream>>>(Tbuf, cum, Sprev);
  k_chunkYout<<<dim3(512, 2), 256, 0, stream>>>(xbca, dts, cum, Sprev, mam_D, zTb,
                                                mam_norm_w, mam_out_w, s2a, s2b);
  k_fcout<<<dim3(64, 8, 2), 256, 0, stream>>>(s2a, s2b, fc_out_w, o3, bnst);
  k_final<<<dim3(64, 8, 2), 256, 0, stream>>>(o3, bnst, bn_g, bn_b, conv4_w, conv4_b, x, out);
}

// Round 4
// 207.847 us; speedup vs baseline: 1.3066x; 1.3066x over previous
//
#include <hip/hip_runtime.h>
#include <math.h>

// Problem constants
constexpr int Bn = 8, Cn = 128, Ln = 4096;

// Workspace layout (float offsets). z (transposed) / s / xbca / Sprev stored as bf16.
constexpr size_t OFF_O1   = 0;          // o1; later o3 (aliased)
constexpr size_t OFF_O2   = 4194304;
constexpr size_t OFF_S    = 8388608;    // bf16: 8*4096*32 ushort
constexpr size_t OFF_Z    = 9437184;    // bf16 zT[dir][p=64][b=8][l=4096]
constexpr size_t OFF_WT   = 11534336;   // bf16 WT[dir][n=272][k=32]
constexpr size_t OFF_XBCA = 13631488;   // bf16: 2 dirs x 6,291,456 ushort
constexpr size_t OFF_DTS  = 26214400;
constexpr size_t OFF_CUM  = 26279936;
constexpr size_t OFF_T    = 26345472;   // 2 dirs x 2,097,152 floats; reused for BN partials
constexpr size_t OFF_SPREV= 30539776;   // bf16: 2 dirs x 2,097,152 ushort
constexpr size_t OFF_S2A  = 34734080;
constexpr size_t OFF_S2B  = 35782656;
constexpr size_t OFF_BN   = 36831232;
constexpr size_t OFF_O3   = 0;

constexpr long XSTRIDE_H = 6291456;   // ushort elements per dir
constexpr long TSTRIDE = 2097152;     // element stride per dir (f32 for T, u16 for Sprev)

typedef __attribute__((ext_vector_type(8))) short short8;
typedef __attribute__((ext_vector_type(4))) float f32x4;
typedef __attribute__((ext_vector_type(4))) unsigned short us4;

__device__ __forceinline__ float siluf(float v) { return v / (1.0f + expf(-v)); }

__device__ __forceinline__ unsigned short tobf(float f) {
  unsigned int u = __float_as_uint(f);
  u += 0x7FFFu + ((u >> 16) & 1u);     // RNE
  return (unsigned short)(u >> 16);
}

__device__ __forceinline__ float frombf(unsigned short u) {
  return __uint_as_float(((unsigned int)u) << 16);
}

// 8 consecutive bf16 from LDS via 4 dword reads (>=4B-aligned offsets)
__device__ __forceinline__ short8 ldfrag(const unsigned short* p) {
  union { unsigned int u[4]; short8 s; } cv;
  cv.u[0] = *(const unsigned int*)(p);
  cv.u[1] = *(const unsigned int*)(p + 2);
  cv.u[2] = *(const unsigned int*)(p + 4);
  cv.u[3] = *(const unsigned int*)(p + 6);
  return cv.s;
}

// K1: o1[b,c,l] = sum_k x[b,k,l]*w[k,c] + bias[c] — MFMA bf16, K=128.
__global__ __launch_bounds__(256) void k_lin1(const float* __restrict__ x,
                                              const float* __restrict__ w,
                                              const float* __restrict__ bias,
                                              float* __restrict__ o1) {
  __shared__ unsigned short wT[64][140];
  __shared__ unsigned short xT[64][140];
  int b = blockIdx.y, l0 = blockIdx.x * 64, cb = blockIdx.z * 64;
  int tid = threadIdx.x, lane = tid & 63, mt = tid >> 6;
  int q = lane >> 4, i = lane & 15;
  int c4 = (tid & 15) * 4, k0 = tid >> 4;
#pragma unroll
  for (int s = 0; s < 8; ++s) {
    int k = k0 + s * 16;
    float4 wv = *(const float4*)&w[k * 128 + cb + c4];
    wT[c4 + 0][k] = tobf(wv.x); wT[c4 + 1][k] = tobf(wv.y);
    wT[c4 + 2][k] = tobf(wv.z); wT[c4 + 3][k] = tobf(wv.w);
    float4 xv = *(const float4*)&x[((long)b * 128 + k) * 4096 + l0 + c4];
    xT[c4 + 0][k] = tobf(xv.x); xT[c4 + 1][k] = tobf(xv.y);
    xT[c4 + 2][k] = tobf(xv.z); xT[c4 + 3][k] = tobf(xv.w);
  }
  __syncthreads();
  short8 af[4];
#pragma unroll
  for (int kk = 0; kk < 4; ++kk)
    af[kk] = ldfrag(&wT[mt * 16 + i][q * 8 + 32 * kk]);
  float bv[4];
#pragma unroll
  for (int r2 = 0; r2 < 4; ++r2) bv[r2] = bias[cb + 16 * mt + q * 4 + r2];
#pragma unroll
  for (int nt = 0; nt < 4; ++nt) {
    f32x4 d = {0.f, 0.f, 0.f, 0.f};
#pragma unroll
    for (int kk = 0; kk < 4; ++kk) {
      short8 bfr = ldfrag(&xT[nt * 16 + i][q * 8 + 32 * kk]);
      d = __builtin_amdgcn_mfma_f32_16x16x32_bf16(af[kk], bfr, d, 0, 0, 0);
    }
#pragma unroll
    for (int r2 = 0; r2 < 4; ++r2) {
      int c = 16 * mt + q * 4 + r2;
      o1[((long)b * 128 + cb + c) * 4096 + l0 + nt * 16 + i] = d[r2] + bv[r2];
    }
  }
}

// K2: depthwise 3x3 SAME + bias + silu. 4x4 patch per thread from LDS plane.
__global__ void k_dw(const float* __restrict__ o1, const float* __restrict__ wgt,
                     const float* __restrict__ bias, float* __restrict__ o2) {
  __shared__ float p[4096];
  int bc = blockIdx.x, c = bc & 127, tid = threadIdx.x;
  const float* src = o1 + (long)bc * 4096;
#pragma unroll
  for (int s4 = 0; s4 < 4; ++s4) {
    int off = s4 * 1024 + tid * 4;
    *(float4*)&p[off] = *(const float4*)&src[off];
  }
  float wr[9];
#pragma unroll
  for (int j = 0; j < 9; ++j) wr[j] = wgt[c * 9 + j];
  float bv = bias[c];
  __syncthreads();
  int wg = tid & 15, hs = tid >> 4;
  int w0 = wg * 4, h0 = hs * 4;
  float in[6][6];
#pragma unroll
  for (int ri = 0; ri < 6; ++ri) {
    int h = h0 - 1 + ri;
    if (h < 0 || h > 63) {
#pragma unroll
      for (int ci = 0; ci < 6; ++ci) in[ri][ci] = 0.f;
    } else {
      float4 cc = *(float4*)&p[h * 64 + w0];
      in[ri][1] = cc.x; in[ri][2] = cc.y; in[ri][3] = cc.z; in[ri][4] = cc.w;
      in[ri][0] = (w0 > 0) ? p[h * 64 + w0 - 1] : 0.f;
      in[ri][5] = (w0 < 60) ? p[h * 64 + w0 + 4] : 0.f;
    }
  }
#pragma unroll
  for (int r = 0; r < 4; ++r) {
    float oc[4];
#pragma unroll
    for (int q = 0; q < 4; ++q) {
      float acc = bv;
#pragma unroll
      for (int dh = 0; dh < 3; ++dh)
#pragma unroll
        for (int dq = 0; dq < 3; ++dq)
          acc += in[r + dh][q + dq] * wr[dh * 3 + dq];
      oc[q] = siluf(acc);
    }
    *(float4*)&o2[(long)bc * 4096 + (h0 + r) * 64 + w0] =
        make_float4(oc[0], oc[1], oc[2], oc[3]);
  }
}

// K3: s[b,l,d] = sum_c o2[b,c,l]*w[c,d] (d<32). Output bf16. Also folds prepW
// (one-time Win -> bf16 transpose) into blocks (x<2, y==0).
__global__ void k_fcin(const float* __restrict__ o2, const float* __restrict__ w,
                       unsigned short* __restrict__ sb,
                       const float* __restrict__ Win, unsigned short* __restrict__ WT) {
  __shared__ float xt[128][64];
  __shared__ float wt[128][32];
  int b = blockIdx.y, l0 = blockIdx.x * 64;
  int tid = threadIdx.x;
  int f4 = (tid & 15) * 4, r0 = tid >> 4;
#pragma unroll
  for (int st = 0; st < 8; ++st) {
    int r = r0 + st * 16;
    *(float4*)&xt[r][f4] = *(const float4*)&o2[((long)b * 128 + r) * 4096 + l0 + f4];
  }
  int f4w = (tid & 7) * 4, rw = tid >> 3;
#pragma unroll
  for (int st = 0; st < 4; ++st) {
    int r = rw + st * 32;
    *(float4*)&wt[r][f4w] = *(const float4*)&w[r * 32 + f4w];
  }
  __syncthreads();
  int tx = tid & 15, ty = tid >> 4;
  int c0 = tx * 4, d0 = ty * 2;
  float acc[2][4] = {};
  for (int k = 0; k < 128; ++k) {
    float4 xv = *(float4*)&xt[k][c0];
    float2 wv = *(float2*)&wt[k][d0];
    float xa[4] = {xv.x, xv.y, xv.z, xv.w};
#pragma unroll
    for (int q = 0; q < 4; ++q) {
      acc[0][q] += wv.x * xa[q];
      acc[1][q] += wv.y * xa[q];
    }
  }
#pragma unroll
  for (int q = 0; q < 4; ++q) {
    long ob = ((long)b * 4096 + l0 + c0 + q) * 32 + d0;
    unsigned int pk = (unsigned int)tobf(acc[0][q]) |
                      ((unsigned int)tobf(acc[1][q]) << 16);
    *(unsigned int*)&sb[ob] = pk;
  }
  // ---- folded prepW: WT[dir][n(272 padded)][k(32)], zeros n>=257 ----
  if (blockIdx.y == 0 && blockIdx.x < 2) {
    int dir = blockIdx.x;
    for (int idx = tid; idx < 272 * 32; idx += 256) {
      int n = idx >> 5, kk = idx & 31;
      float v = (n < 257) ? Win[dir * 32 * 257 + kk * 257 + n] : 0.f;
      WT[dir * 8704 + idx] = tobf(v);
    }
  }
}

// K4: in_proj (MFMA bf16, K=32) + causal conv1d + silu + dt softplus + cum
//     + fused chunk summary T[p][n] = sum_s f_s*X_s[p]*B_s[n] (MFMA bf16).
__global__ __launch_bounds__(256) void k_inprojconv(
    const unsigned short* __restrict__ sb, const unsigned short* __restrict__ WT,
    const float* __restrict__ conv_w, const float* __restrict__ conv_b,
    const float* __restrict__ dt_bias, const float* __restrict__ A_log,
    unsigned short* __restrict__ zT, unsigned short* __restrict__ xbca,
    float* __restrict__ dts, float* __restrict__ cum, float* __restrict__ Tg) {
  __shared__ unsigned short xbcT[192][82];   // [channel][t], pitch 82: conflict-free
  __shared__ float fXf[64][68];              // fp32 silu(X) for T's A-operand
  __shared__ float dtL[64];                  // raw dt MFMA outputs
  __shared__ float dtsS[64], cumSS[64], fL[64];
  int dir = blockIdx.z, b = blockIdx.y, l0 = blockIdx.x * 64;
  int tid = threadIdx.x, lane = tid & 63, mt = tid >> 6;
  int q = lane >> 4, i = lane & 15;
  long rowbase = (long)b * 4096 + l0;
  const unsigned short* W = WT + (long)dir * 8704;
  const short8 zfrag = {0, 0, 0, 0, 0, 0, 0, 0};

  if (mt == 0) {
    // ---- z columns (n 0..63) + dt column, l0-aligned rows ----
    short8 afr[4];
#pragma unroll
    for (int rt = 0; rt < 4; ++rt) {
      int l = l0 + 16 * rt + i;
      int lsrc = dir ? (4095 - l) : l;
      afr[rt] = *(const short8*)&sb[((long)b * 4096 + lsrc) * 32 + q * 8];
    }
#pragma unroll
    for (int ct = 0; ct < 4; ++ct) {
      int n = 16 * ct + i;
      short8 bfr = *(const short8*)&W[n * 32 + q * 8];
      unsigned short* zrow = zT + (((long)dir * 64 + n) * 8 + b) * 4096 + l0 + q * 4;
#pragma unroll
      for (int rt = 0; rt < 4; ++rt) {
        f32x4 d = {0.f, 0.f, 0.f, 0.f};
        d = __builtin_amdgcn_mfma_f32_16x16x32_bf16(afr[rt], bfr, d, 0, 0, 0);
        us4 pk;
        pk[0] = tobf(d[0]); pk[1] = tobf(d[1]);
        pk[2] = tobf(d[2]); pk[3] = tobf(d[3]);
        *(us4*)&zrow[16 * rt] = pk;
      }
    }
    {
      short8 bfr = *(const short8*)&W[(256 + i) * 32 + q * 8];
#pragma unroll
      for (int rt = 0; rt < 4; ++rt) {
        f32x4 d = {0.f, 0.f, 0.f, 0.f};
        d = __builtin_amdgcn_mfma_f32_16x16x32_bf16(afr[rt], bfr, d, 0, 0, 0);
        if (i == 0) {
#pragma unroll
          for (int r2 = 0; r2 < 4; ++r2) dtL[16 * rt + q * 4 + r2] = d[r2];
        }
      }
    }
  } else {
    // ---- xbc columns (n 64..255), rows with -3 conv halo ----
    short8 afr[5];
#pragma unroll
    for (int rt = 0; rt < 5; ++rt) {
      int l = l0 - 3 + 16 * rt + i;
      if (l >= 0 && l < 4096) {
        int lsrc = dir ? (4095 - l) : l;
        afr[rt] = *(const short8*)&sb[((long)b * 4096 + lsrc) * 32 + q * 8];
      } else {
        afr[rt] = zfrag;
      }
    }
#pragma unroll
    for (int cti = 0; cti < 4; ++cti) {
      int n = 16 * (mt * 4 + cti) + i;
      short8 bfr = *(const short8*)&W[n * 32 + q * 8];
      int cc = n - 64;
#pragma unroll
      for (int rt = 0; rt < 5; ++rt) {
        f32x4 d = {0.f, 0.f, 0.f, 0.f};
        d = __builtin_amdgcn_mfma_f32_16x16x32_bf16(afr[rt], bfr, d, 0, 0, 0);
        int rr0 = 16 * rt + q * 4;
        unsigned int p0 = (unsigned int)tobf(d[0]) | ((unsigned int)tobf(d[1]) << 16);
        unsigned int p1 = (unsigned int)tobf(d[2]) | ((unsigned int)tobf(d[3]) << 16);
        *(unsigned int*)&xbcT[cc][rr0] = p0;
        *(unsigned int*)&xbcT[cc][rr0 + 2] = p1;
      }
    }
  }
  __syncthreads();

  if (tid < 192) {
    int c = tid;
    float cw0 = conv_w[dir * 768 + c * 4 + 0];
    float cw1 = conv_w[dir * 768 + c * 4 + 1];
    float cw2 = conv_w[dir * 768 + c * 4 + 2];
    float cw3 = conv_w[dir * 768 + c * 4 + 3];
    float cb2 = conv_b[dir * 192 + c];
    unsigned short* xp = xbca + (long)dir * XSTRIDE_H;
    float win0 = 0.f, win1 = 0.f, win2 = 0.f, win3 = 0.f;
    for (int rp = 0; rp < 34; ++rp) {
      unsigned int pk = *(const unsigned int*)&xbcT[c][rp * 2];
      float a0 = frombf((unsigned short)(pk & 0xFFFFu));
      float a1 = frombf((unsigned short)(pk >> 16));
      int rr = rp * 2;
      win0 = win1; win1 = win2; win2 = win3; win3 = a0;
      if (rr >= 3 && rr <= 66) {
        float acc = cb2 + win0 * cw0 + win1 * cw1 + win2 * cw2 + win3 * cw3;
        float sv = siluf(acc);
        int t = rr - 3;
        xp[(rowbase + t) * 192 + c] = tobf(sv);
        if (c < 64) fXf[c][t] = sv;                        // fp32 X for T
        else if (c < 128) xbcT[c][t] = tobf(sv);           // bf16 B for T (trails reads by 3)
      }
      win0 = win1; win1 = win2; win2 = win3; win3 = a1;
      if (rr + 1 >= 3 && rr + 1 <= 66) {
        float acc = cb2 + win0 * cw0 + win1 * cw1 + win2 * cw2 + win3 * cw3;
        float sv = siluf(acc);
        int t = rr - 2;
        xp[(rowbase + t) * 192 + c] = tobf(sv);
        if (c < 64) fXf[c][t] = sv;
        else if (c < 128) xbcT[c][t] = tobf(sv);
      }
    }
  } else {
    int ln = tid - 192;
    float v = dtL[ln] + dt_bias[dir];
    float sp = (v > 20.f) ? v : log1pf(expf(v));
    dts[dir * 32768 + rowbase + ln] = sp;
    dtsS[ln] = sp;
    float cd = -expf(A_log[dir]) * sp;
#pragma unroll
    for (int off = 1; off < 64; off <<= 1) {
      float u = __shfl_up(cd, off);
      if (ln >= off) cd += u;
    }
    cum[dir * 32768 + rowbase + ln] = cd;
    cumSS[ln] = cd;
  }
  __syncthreads();

  if (tid < 64) fL[tid] = expf(cumSS[63] - cumSS[tid]) * dtsS[tid];
  __syncthreads();

  // scale phase: xbcT rows 0..63 <- tobf(fXf * fL)
  {
    int c = tid & 63, tb2 = (tid >> 6) * 16;
#pragma unroll
    for (int j = 0; j < 8; ++j) {
      int t = tb2 + 2 * j;
      float2 v = *(const float2*)&fXf[c][t];
      unsigned int pk = (unsigned int)tobf(v.x * fL[t]) |
                        ((unsigned int)tobf(v.y * fL[t + 1]) << 16);
      *(unsigned int*)&xbcT[c][t] = pk;
    }
  }
  __syncthreads();

  // MFMA-T: T[p][n] = sum_t fX[p][t] * B[n][t], K=64 (two K=32 MFMAs)
  {
    short8 a0 = ldfrag(&xbcT[mt * 16 + i][q * 8]);
    short8 a1 = ldfrag(&xbcT[mt * 16 + i][q * 8 + 32]);
    float* Tp = Tg + (long)dir * TSTRIDE + ((long)(b * 64 + blockIdx.x)) * 4096;
#pragma unroll
    for (int nt = 0; nt < 4; ++nt) {
      short8 b0 = ldfrag(&xbcT[64 + nt * 16 + i][q * 8]);
      short8 b1 = ldfrag(&xbcT[64 + nt * 16 + i][q * 8 + 32]);
      f32x4 d = {0.f, 0.f, 0.f, 0.f};
      d = __builtin_amdgcn_mfma_f32_16x16x32_bf16(a0, b0, d, 0, 0, 0);
      d = __builtin_amdgcn_mfma_f32_16x16x32_bf16(a1, b1, d, 0, 0, 0);
#pragma unroll
      for (int r2 = 0; r2 < 4; ++r2)
        Tp[(mt * 16 + q * 4 + r2) * 64 + nt * 16 + i] = d[r2];
    }
  }
}

// K7: inter-chunk state scan — pn-pairs, 16-deep prefetch, bf16 output.
__global__ void k_scan(const float* __restrict__ T, const float* __restrict__ cum,
                       unsigned short* __restrict__ Sprev) {
  __shared__ float E[64];
  int blk = blockIdx.x;            // 128 blocks
  int dirb = blk >> 3;             // dir*8 + b
  int dir = dirb >> 3, b = dirb & 7;
  int pn = (blk & 7) * 512 + threadIdx.x * 2;
  const float* cp = cum + dir * 32768 + b * 4096;
  if (threadIdx.x < 64) E[threadIdx.x] = expf(cp[threadIdx.x * 64 + 63]);
  __syncthreads();
  const float* Tp = T + (long)dir * TSTRIDE + (long)b * 262144 + pn;
  unsigned short* Sp = Sprev + (long)dir * TSTRIDE + (long)b * 262144 + pn;
  float s0 = 0.f, s1 = 0.f;
  float2 tb[16];
#pragma unroll
  for (int j = 0; j < 16; ++j) tb[j] = *(const float2*)&Tp[(long)j * 4096];
  for (int kc = 0; kc < 4; ++kc) {
    float2 tn[16];
    if (kc < 3) {
#pragma unroll
      for (int j = 0; j < 16; ++j)
        tn[j] = *(const float2*)&Tp[(long)(kc * 16 + 16 + j) * 4096];
    }
#pragma unroll
    for (int j = 0; j < 16; ++j) {
      int k = kc * 16 + j;
      unsigned int pk = (unsigned int)tobf(s0) | ((unsigned int)tobf(s1) << 16);
      *(unsigned int*)&Sp[(long)k * 4096] = pk;
      s0 = fmaf(E[k], s0, tb[j].x);
      s1 = fmaf(E[k], s1, tb[j].y);
    }
    if (kc < 3) {
#pragma unroll
      for (int j = 0; j < 16; ++j) tb[j] = tn[j];
    }
  }
}

// K8: per-chunk Y + gate + RMSNorm + out-proj — MFMA bf16, vectorized staging.
__global__ __launch_bounds__(256) void k_chunkYout(
    const unsigned short* __restrict__ xbca, const float* __restrict__ dts,
    const float* __restrict__ cum, const unsigned short* __restrict__ Sprev,
    const float* __restrict__ Dp, const unsigned short* __restrict__ zT,
    const float* __restrict__ normw, const float* __restrict__ Wout,
    float* __restrict__ s2a, float* __restrict__ s2b) {
  __shared__ unsigned short Cb[64][72];
  __shared__ unsigned short Bop[64][68];
  __shared__ unsigned short Gb[64][72];
  __shared__ unsigned short WnT[32][66];
  __shared__ float cumS[64];
  int dir = blockIdx.y;
  int bk = blockIdx.x, b = bk >> 6, k = bk & 63;
  int tid = threadIdx.x, lane = tid & 63, mt = tid >> 6;
  int q = lane >> 4, i = lane & 15;
  const unsigned short* xp = xbca + (long)dir * XSTRIDE_H;
  const float* dtp = dts + dir * 32768;
  const float* cp = cum + dir * 32768;
  const unsigned short* Sp = Sprev + (long)dir * TSTRIDE;
  long base = (long)b * 4096 + (long)k * 64;

  {
    int c4 = (tid & 15) * 4, r0 = tid >> 4;
#pragma unroll
    for (int s = 0; s < 4; ++s) {
      int r = r0 + s * 16;
      float dtv = dtp[base + r];
      const unsigned short* rowp = &xp[(base + r) * 192 + 64];
      us4 bv = *(const us4*)&rowp[c4];
      us4 cv = *(const us4*)&rowp[64 + c4];
      us4 bo;
#pragma unroll
      for (int j = 0; j < 4; ++j) bo[j] = tobf(frombf(bv[j]) * dtv);
      *(us4*)&Bop[r][c4] = bo;
      *(us4*)&Cb[r][c4] = cv;
    }
  }
  for (int idx = tid; idx < 2048; idx += 256) {
    int p = idx >> 5, d = idx & 31;
    WnT[d][p] = tobf(normw[dir * 64 + p] * Wout[(long)dir * 2048 + p * 32 + d]);
  }
  if (tid < 64) cumS[tid] = cp[base + tid];
  __syncthreads();

  short8 a0 = *(const short8*)&Cb[mt * 16 + i][q * 8];
  short8 a1 = *(const short8*)&Cb[mt * 16 + i][q * 8 + 32];

#pragma unroll
  for (int lt = 0; lt < 4; ++lt) {
    short8 b0 = ldfrag(&Bop[lt * 16 + i][q * 8]);
    short8 b1 = ldfrag(&Bop[lt * 16 + i][q * 8 + 32]);
    f32x4 d = {0.f, 0.f, 0.f, 0.f};
    d = __builtin_amdgcn_mfma_f32_16x16x32_bf16(a0, b0, d, 0, 0, 0);
    d = __builtin_amdgcn_mfma_f32_16x16x32_bf16(a1, b1, d, 0, 0, 0);
#pragma unroll
    for (int r2 = 0; r2 < 4; ++r2) {
      int t = mt * 16 + q * 4 + r2;
      int l = lt * 16 + i;
      float g = (l <= t) ? d[r2] * expf(cumS[t] - cumS[l]) : 0.f;
      Gb[t][l] = tobf(g);
    }
  }
  __syncthreads();

  {
    int c4 = (tid & 15) * 4, r0 = tid >> 4;
#pragma unroll
    for (int s = 0; s < 4; ++s) {
      int r = r0 + s * 16;
      us4 sv = *(const us4*)&Sp[(long)bk * 4096 + r * 64 + c4];
      *(us4*)&Bop[r][c4] = sv;
    }
  }
  __syncthreads();

  f32x4 dint[4];
#pragma unroll
  for (int lt = 0; lt < 4; ++lt) {
    short8 b0 = ldfrag(&Bop[lt * 16 + i][q * 8]);
    short8 b1 = ldfrag(&Bop[lt * 16 + i][q * 8 + 32]);
    f32x4 d = {0.f, 0.f, 0.f, 0.f};
    d = __builtin_amdgcn_mfma_f32_16x16x32_bf16(a0, b0, d, 0, 0, 0);
    d = __builtin_amdgcn_mfma_f32_16x16x32_bf16(a1, b1, d, 0, 0, 0);
    dint[lt] = d;
  }
  __syncthreads();

  // Repack X transposed into Bop: Bop[p][t] = X[row t][channel p]
#pragma unroll
  for (int j = 0; j < 8; ++j) {
    int s = mt * 16 + 2 * j;
    unsigned int pk = (unsigned int)xp[(base + s) * 192 + lane] |
                      ((unsigned int)xp[(base + s + 1) * 192 + lane] << 16);
    *(unsigned int*)&Bop[lane][s] = pk;
  }
  __syncthreads();

  short8 g0 = *(const short8*)&Gb[mt * 16 + i][q * 8];
  short8 g1 = *(const short8*)&Gb[mt * 16 + i][q * 8 + 32];
  float Dv = Dp[dir];
  float et4[4];
#pragma unroll
  for (int r2 = 0; r2 < 4; ++r2) et4[r2] = expf(cumS[mt * 16 + q * 4 + r2]);
  float yv[4][4];
  float rowss[4] = {0.f, 0.f, 0.f, 0.f};
#pragma unroll
  for (int lt = 0; lt < 4; ++lt) {
    short8 b0 = ldfrag(&Bop[lt * 16 + i][q * 8]);
    short8 b1 = ldfrag(&Bop[lt * 16 + i][q * 8 + 32]);
    f32x4 d = {0.f, 0.f, 0.f, 0.f};
    d = __builtin_amdgcn_mfma_f32_16x16x32_bf16(g0, b0, d, 0, 0, 0);
    d = __builtin_amdgcn_mfma_f32_16x16x32_bf16(g1, b1, d, 0, 0, 0);
    us4 zq = *(const us4*)&zT[(((long)dir * 64 + lt * 16 + i) * 8 + b) * 4096 +
                              (long)k * 64 + mt * 16 + q * 4];
    unsigned int xpk0 = *(const unsigned int*)&Bop[lt * 16 + i][mt * 16 + q * 4];
    unsigned int xpk1 = *(const unsigned int*)&Bop[lt * 16 + i][mt * 16 + q * 4 + 2];
    float xvr[4];
    xvr[0] = frombf((unsigned short)(xpk0 & 0xFFFFu));
    xvr[1] = frombf((unsigned short)(xpk0 >> 16));
    xvr[2] = frombf((unsigned short)(xpk1 & 0xFFFFu));
    xvr[3] = frombf((unsigned short)(xpk1 >> 16));
#pragma unroll
    for (int r2 = 0; r2 < 4; ++r2) {
      float y = d[r2] + et4[r2] * dint[lt][r2] + Dv * xvr[r2];
      float zv = frombf(zq[r2]);
      float v = y * siluf(zv);
      yv[lt][r2] = v;
      rowss[r2] += v * v;
    }
  }
#pragma unroll
  for (int m = 1; m < 16; m <<= 1) {
#pragma unroll
    for (int r2 = 0; r2 < 4; ++r2) rowss[r2] += __shfl_xor(rowss[r2], m);
  }
  float rscv[4];
#pragma unroll
  for (int r2 = 0; r2 < 4; ++r2)
    rscv[r2] = rsqrtf(rowss[r2] * (1.0f / 64.0f) + 1e-5f);
#pragma unroll
  for (int lt = 0; lt < 4; ++lt)
#pragma unroll
    for (int r2 = 0; r2 < 4; ++r2) {
      int t = mt * 16 + q * 4 + r2;
      int p = lt * 16 + i;
      Gb[t][p] = tobf(yv[lt][r2] * rscv[r2]);
    }
  __syncthreads();

  short8 y0 = *(const short8*)&Gb[mt * 16 + i][q * 8];
  short8 y1 = *(const short8*)&Gb[mt * 16 + i][q * 8 + 32];
  float* s2x = dir ? s2b : s2a;
#pragma unroll
  for (int dt = 0; dt < 2; ++dt) {
    short8 b0 = ldfrag(&WnT[dt * 16 + i][q * 8]);
    short8 b1 = ldfrag(&WnT[dt * 16 + i][q * 8 + 32]);
    f32x4 d = {0.f, 0.f, 0.f, 0.f};
    d = __builtin_amdgcn_mfma_f32_16x16x32_bf16(y0, b0, d, 0, 0, 0);
    d = __builtin_amdgcn_mfma_f32_16x16x32_bf16(y1, b1, d, 0, 0, 0);
#pragma unroll
    for (int r2 = 0; r2 < 4; ++r2) {
      int tl = mt * 16 + q * 4 + r2;
      int l = k * 64 + tl;
      int lout = dir ? (4095 - l) : l;
      int dd = dt * 16 + i;
      s2x[((long)b * 4096 + lout) * 32 + dd] = d[r2];
    }
  }
}

// K10: o3 = (s2a+s2b)@W — GEMM + BN partial sums to scratch (NO atomics).
__global__ void k_fcout(const float* __restrict__ s2a, const float* __restrict__ s2b,
                        const float* __restrict__ w, float* __restrict__ o3,
                        float* __restrict__ part) {
  __shared__ float st[32][68];
  __shared__ float wt[32][64];
  int b = blockIdx.y, l0 = blockIdx.x * 64, cb = blockIdx.z * 64;
  int tid = threadIdx.x;
  {
    int d = tid & 31, l = tid >> 5;
    for (int si = 0; si < 8; ++si) {
      int ll = l + si * 8;
      long o = ((long)b * 4096 + l0 + ll) * 32 + d;
      st[d][ll] = s2a[o] + s2b[o];
    }
    int f4 = (tid & 15) * 4, r = tid >> 4;
    for (int si = 0; si < 2; ++si) {
      int rr = r + si * 16;
      *(float4*)&wt[rr][f4] = *(const float4*)&w[rr * 128 + cb + f4];
    }
  }
  __syncthreads();
  int tx = tid & 15, ty = tid >> 4;
  int c0 = tx * 4, t0 = ty * 4;
  float acc[4][4] = {};
  for (int k = 0; k < 32; ++k) {
    float4 xv = *(float4*)&st[k][c0];
    float4 wv = *(float4*)&wt[k][t0];
    float xa[4] = {xv.x, xv.y, xv.z, xv.w};
    float wa[4] = {wv.x, wv.y, wv.z, wv.w};
#pragma unroll
    for (int a = 0; a < 4; ++a)
#pragma unroll
      for (int q = 0; q < 4; ++q) acc[a][q] += wa[a] * xa[q];
  }
#pragma unroll
  for (int a = 0; a < 4; ++a)
    *(float4*)&o3[((long)b * 128 + cb + t0 + a) * 4096 + l0 + c0] =
        make_float4(acc[a][0], acc[a][1], acc[a][2], acc[a][3]);
  // ---- BN partial sums: reduce over the 16 l-lanes, store per-block partials ----
  float ssum[4], sqq[4];
#pragma unroll
  for (int a = 0; a < 4; ++a) {
    ssum[a] = acc[a][0] + acc[a][1] + acc[a][2] + acc[a][3];
    sqq[a] = acc[a][0] * acc[a][0] + acc[a][1] * acc[a][1] +
             acc[a][2] * acc[a][2] + acc[a][3] * acc[a][3];
  }
#pragma unroll
  for (int m = 1; m < 16; m <<= 1) {
#pragma unroll
    for (int a = 0; a < 4; ++a) {
      ssum[a] += __shfl_xor(ssum[a], m);
      sqq[a] += __shfl_xor(sqq[a], m);
    }
  }
  if (tx == 0) {
    int idx = b * 64 + blockIdx.x;   // 512 slots per channel
#pragma unroll
    for (int a = 0; a < 4; ++a) {
      int ch = cb + t0 + a;
      part[(long)ch * 512 + idx] = ssum[a];
      part[65536 + (long)ch * 512 + idx] = sqq[a];
    }
  }
}

// K11: reduce BN partials (128 blocks = 1 per channel). No atomics anywhere.
__global__ void k_bnred(const float* __restrict__ part, float* __restrict__ stats) {
  int ch = blockIdx.x, tid = threadIdx.x;
  float s = part[(long)ch * 512 + tid] + part[(long)ch * 512 + 256 + tid];
  float q = part[65536 + (long)ch * 512 + tid] +
            part[65536 + (long)ch * 512 + 256 + tid];
  for (int off = 32; off; off >>= 1) {
    s += __shfl_down(s, off);
    q += __shfl_down(q, off);
  }
  __shared__ float rs[4], rq[4];
  if ((tid & 63) == 0) { rs[tid >> 6] = s; rq[tid >> 6] = q; }
  __syncthreads();
  if (tid == 0) {
    stats[ch] = rs[0] + rs[1] + rs[2] + rs[3];
    stats[128 + ch] = rq[0] + rq[1] + rq[2] + rq[3];
  }
}

// K12: BN + conv4 + sigmoid + gated residual — MFMA bf16 (BN folded in staging).
__global__ __launch_bounds__(256) void k_final(const float* __restrict__ o3,
                                               const float* __restrict__ stats,
                                               const float* __restrict__ bng,
                                               const float* __restrict__ bnb,
                                               const float* __restrict__ w,
                                               const float* __restrict__ bias,
                                               const float* __restrict__ x,
                                               float* __restrict__ out) {
  __shared__ unsigned short wT[64][140];
  __shared__ unsigned short aT[64][140];
  __shared__ float sc[128], sh[128];
  int b = blockIdx.y, l0 = blockIdx.x * 64, cb = blockIdx.z * 64;
  int tid = threadIdx.x, lane = tid & 63, mt = tid >> 6;
  int q = lane >> 4, i = lane & 15;
  if (tid < 128) {
    float mu = stats[tid] * (1.0f / 32768.0f);
    float var = stats[128 + tid] * (1.0f / 32768.0f) - mu * mu;
    float r = rsqrtf(var + 1e-5f);
    sc[tid] = r * bng[tid];
    sh[tid] = bnb[tid] - mu * r * bng[tid];
  }
  __syncthreads();
  int c4 = (tid & 15) * 4, k0 = tid >> 4;
#pragma unroll
  for (int s = 0; s < 8; ++s) {
    int k = k0 + s * 16;
    float4 wv = *(const float4*)&w[k * 128 + cb + c4];
    wT[c4 + 0][k] = tobf(wv.x); wT[c4 + 1][k] = tobf(wv.y);
    wT[c4 + 2][k] = tobf(wv.z); wT[c4 + 3][k] = tobf(wv.w);
    float4 av = *(const float4*)&o3[((long)b * 128 + k) * 4096 + l0 + c4];
    float scr = sc[k], shr = sh[k];
    aT[c4 + 0][k] = tobf(fmaf(av.x, scr, shr));
    aT[c4 + 1][k] = tobf(fmaf(av.y, scr, shr));
    aT[c4 + 2][k] = tobf(fmaf(av.z, scr, shr));
    aT[c4 + 3][k] = tobf(fmaf(av.w, scr, shr));
  }
  __syncthreads();
  short8 af[4];
#pragma unroll
  for (int kk = 0; kk < 4; ++kk)
    af[kk] = ldfrag(&wT[mt * 16 + i][q * 8 + 32 * kk]);
  float bv[4];
#pragma unroll
  for (int r2 = 0; r2 < 4; ++r2) bv[r2] = bias[cb + 16 * mt + q * 4 + r2];
#pragma unroll
  for (int nt = 0; nt < 4; ++nt) {
    f32x4 d = {0.f, 0.f, 0.f, 0.f};
#pragma unroll
    for (int kk = 0; kk < 4; ++kk) {
      short8 bfr = ldfrag(&aT[nt * 16 + i][q * 8 + 32 * kk]);
      d = __builtin_amdgcn_mfma_f32_16x16x32_bf16(af[kk], bfr, d, 0, 0, 0);
    }
#pragma unroll
    for (int r2 = 0; r2 < 4; ++r2) {
      int c = 16 * mt + q * 4 + r2;
      long xi = ((long)b * 128 + cb + c) * 4096 + l0 + nt * 16 + i;
      float g = 1.0f / (1.0f + expf(-(d[r2] + bv[r2])));
      out[xi] = x[xi] * (1.0f + g);
    }
  }
}

extern "C" void kernel_launch(void* const* d_in, const int* in_sizes, int n_in,
                              void* d_out, int out_size, void* d_ws, size_t ws_size,
                              hipStream_t stream) {
  const float* x          = (const float*)d_in[0];
  const float* lin1_w     = (const float*)d_in[1];
  const float* lin1_b     = (const float*)d_in[2];
  const float* dw_w       = (const float*)d_in[3];
  const float* dw_b       = (const float*)d_in[4];
  const float* fc_in_w    = (const float*)d_in[5];
  const float* mam_in_w   = (const float*)d_in[6];
  const float* mam_conv_w = (const float*)d_in[7];
  const float* mam_conv_b = (const float*)d_in[8];
  const float* mam_dt_bias= (const float*)d_in[9];
  const float* mam_A_log  = (const float*)d_in[10];
  const float* mam_D      = (const float*)d_in[11];
  const float* mam_norm_w = (const float*)d_in[12];
  const float* mam_out_w  = (const float*)d_in[13];
  const float* fc_out_w   = (const float*)d_in[14];
  const float* bn_g       = (const float*)d_in[15];
  const float* bn_b       = (const float*)d_in[16];
  const float* conv4_w    = (const float*)d_in[17];
  const float* conv4_b    = (const float*)d_in[18];
  float* out = (float*)d_out;
  float* ws  = (float*)d_ws;

  float* o1   = ws + OFF_O1;
  float* o2   = ws + OFF_O2;
  unsigned short* sbuf = (unsigned short*)(ws + OFF_S);
  unsigned short* zTb  = (unsigned short*)(ws + OFF_Z);
  unsigned short* WTb  = (unsigned short*)(ws + OFF_WT);
  unsigned short* xbca = (unsigned short*)(ws + OFF_XBCA);
  float* dts  = ws + OFF_DTS;
  float* cum  = ws + OFF_CUM;
  float* Tbuf = ws + OFF_T;
  unsigned short* Sprev = (unsigned short*)(ws + OFF_SPREV);
  float* s2a  = ws + OFF_S2A;
  float* s2b  = ws + OFF_S2B;
  float* bnst = ws + OFF_BN;
  float* o3   = ws + OFF_O3;
  float* part = ws + OFF_T;   // Tbuf dead after k_scan; reuse for BN partials

  k_lin1<<<dim3(64, 8, 2), 256, 0, stream>>>(x, lin1_w, lin1_b, o1);
  k_dw<<<1024, 256, 0, stream>>>(o1, dw_w, dw_b, o2);
  k_fcin<<<dim3(64, 8), 256, 0, stream>>>(o2, fc_in_w, sbuf, mam_in_w, WTb);
  k_inprojconv<<<dim3(64, 8, 2), 256, 0, stream>>>(sbuf, WTb, mam_conv_w, mam_conv_b,
                                                   mam_dt_bias, mam_A_log,
                                                   zTb, xbca, dts, cum, Tbuf);
  k_scan<<<128, 256, 0, stream>>>(Tbuf, cum, Sprev);
  k_chunkYout<<<dim3(512, 2), 256, 0, stream>>>(xbca, dts, cum, Sprev, mam_D, zTb,
                                                mam_norm_w, mam_out_w, s2a, s2b);
  k_fcout<<<dim3(64, 8, 2), 256, 0, stream>>>(s2a, s2b, fc_out_w, o3, part);
  k_bnred<<<128, 256, 0, stream>>>(part, bnst);
  k_final<<<dim3(64, 8, 2), 256, 0, stream>>>(o3, bnst, bn_g, bn_b, conv4_w, conv4_b, x, out);
}

// Round 5
// 201.395 us; speedup vs baseline: 1.3485x; 1.0320x over previous
//
#include <hip/hip_runtime.h>
#include <math.h>

// Problem constants
constexpr int Bn = 8, Cn = 128, Ln = 4096;

// Workspace layout (float offsets). o1/o2/o3, z, s, xbca, Sprev stored bf16.
constexpr size_t OFF_O1   = 0;          // bf16 o1; later bf16 o3 (aliased)
constexpr size_t OFF_O2   = 4194304;    // bf16
constexpr size_t OFF_S    = 8388608;    // bf16: 8*4096*32 ushort
constexpr size_t OFF_Z    = 9437184;    // bf16 zT[dir][p=64][b=8][l=4096]
constexpr size_t OFF_WT   = 11534336;   // bf16 WT[dir][n=272][k=32]
constexpr size_t OFF_XBCA = 13631488;   // bf16: 2 dirs x 6,291,456 ushort
constexpr size_t OFF_DTS  = 26214400;
constexpr size_t OFF_CUM  = 26279936;
constexpr size_t OFF_T    = 26345472;   // 2 dirs x 2,097,152 floats; reused for BN partials
constexpr size_t OFF_SPREV= 30539776;   // bf16: 2 dirs x 2,097,152 ushort
constexpr size_t OFF_S2A  = 34734080;
constexpr size_t OFF_S2B  = 35782656;
constexpr size_t OFF_BN   = 36831232;
constexpr size_t OFF_O3   = 0;

constexpr long XSTRIDE_H = 6291456;   // ushort elements per dir
constexpr long TSTRIDE = 2097152;     // element stride per dir (f32 for T, u16 for Sprev)

typedef __attribute__((ext_vector_type(8))) short short8;
typedef __attribute__((ext_vector_type(4))) float f32x4;
typedef __attribute__((ext_vector_type(4))) unsigned short us4;
typedef __attribute__((ext_vector_type(8))) unsigned short us8;

__device__ __forceinline__ float siluf(float v) { return v / (1.0f + expf(-v)); }

__device__ __forceinline__ unsigned short tobf(float f) {
  unsigned int u = __float_as_uint(f);
  u += 0x7FFFu + ((u >> 16) & 1u);     // RNE
  return (unsigned short)(u >> 16);
}

__device__ __forceinline__ float frombf(unsigned short u) {
  return __uint_as_float(((unsigned int)u) << 16);
}

__device__ __forceinline__ unsigned int pk2(float a, float b) {
  return (unsigned int)tobf(a) | ((unsigned int)tobf(b) << 16);
}

// 8 consecutive bf16 from LDS via 4 dword reads (>=4B-aligned offsets)
__device__ __forceinline__ short8 ldfrag(const unsigned short* p) {
  union { unsigned int u[4]; short8 s; } cv;
  cv.u[0] = *(const unsigned int*)(p);
  cv.u[1] = *(const unsigned int*)(p + 2);
  cv.u[2] = *(const unsigned int*)(p + 4);
  cv.u[3] = *(const unsigned int*)(p + 6);
  return cv.s;
}

// K1: o1[b,c,l] = sum_k x[b,k,l]*w[k,c] + bias[c] — MFMA bf16, K=128. bf16 out.
__global__ __launch_bounds__(256) void k_lin1(const float* __restrict__ x,
                                              const float* __restrict__ w,
                                              const float* __restrict__ bias,
                                              unsigned short* __restrict__ o1) {
  __shared__ unsigned short wT[64][140];
  __shared__ unsigned short xT[64][140];
  int b = blockIdx.y, l0 = blockIdx.x * 64, cb = blockIdx.z * 64;
  int tid = threadIdx.x, lane = tid & 63, mt = tid >> 6;
  int q = lane >> 4, i = lane & 15;
  int c4 = (tid & 15) * 4, k0 = (tid >> 4) * 2;
#pragma unroll
  for (int s = 0; s < 4; ++s) {
    int k = k0 + s * 32;
    float4 w0 = *(const float4*)&w[k * 128 + cb + c4];
    float4 w1 = *(const float4*)&w[(k + 1) * 128 + cb + c4];
    *(unsigned int*)&wT[c4 + 0][k] = pk2(w0.x, w1.x);
    *(unsigned int*)&wT[c4 + 1][k] = pk2(w0.y, w1.y);
    *(unsigned int*)&wT[c4 + 2][k] = pk2(w0.z, w1.z);
    *(unsigned int*)&wT[c4 + 3][k] = pk2(w0.w, w1.w);
    float4 x0 = *(const float4*)&x[((long)b * 128 + k) * 4096 + l0 + c4];
    float4 x1 = *(const float4*)&x[((long)b * 128 + k + 1) * 4096 + l0 + c4];
    *(unsigned int*)&xT[c4 + 0][k] = pk2(x0.x, x1.x);
    *(unsigned int*)&xT[c4 + 1][k] = pk2(x0.y, x1.y);
    *(unsigned int*)&xT[c4 + 2][k] = pk2(x0.z, x1.z);
    *(unsigned int*)&xT[c4 + 3][k] = pk2(x0.w, x1.w);
  }
  __syncthreads();
  short8 af[4];
#pragma unroll
  for (int kk = 0; kk < 4; ++kk)
    af[kk] = ldfrag(&wT[mt * 16 + i][q * 8 + 32 * kk]);
  float bv[4];
#pragma unroll
  for (int r2 = 0; r2 < 4; ++r2) bv[r2] = bias[cb + 16 * mt + q * 4 + r2];
#pragma unroll
  for (int nt = 0; nt < 4; ++nt) {
    f32x4 d = {0.f, 0.f, 0.f, 0.f};
#pragma unroll
    for (int kk = 0; kk < 4; ++kk) {
      short8 bfr = ldfrag(&xT[nt * 16 + i][q * 8 + 32 * kk]);
      d = __builtin_amdgcn_mfma_f32_16x16x32_bf16(af[kk], bfr, d, 0, 0, 0);
    }
#pragma unroll
    for (int r2 = 0; r2 < 4; ++r2) {
      int c = 16 * mt + q * 4 + r2;
      o1[((long)b * 128 + cb + c) * 4096 + l0 + nt * 16 + i] = tobf(d[r2] + bv[r2]);
    }
  }
}

// K2: depthwise 3x3 SAME + bias + silu. bf16 in/out, f32 LDS plane + math.
__global__ void k_dw(const unsigned short* __restrict__ o1,
                     const float* __restrict__ wgt,
                     const float* __restrict__ bias, unsigned short* __restrict__ o2) {
  __shared__ float p[4096];
  int bc = blockIdx.x, c = bc & 127, tid = threadIdx.x;
  const unsigned short* src = o1 + (long)bc * 4096;
#pragma unroll
  for (int s4 = 0; s4 < 2; ++s4) {
    int off = s4 * 2048 + tid * 8;
    us8 v = *(const us8*)&src[off];
#pragma unroll
    for (int j = 0; j < 8; ++j) p[off + j] = frombf(v[j]);
  }
  float wr[9];
#pragma unroll
  for (int j = 0; j < 9; ++j) wr[j] = wgt[c * 9 + j];
  float bv = bias[c];
  __syncthreads();
  int wg = tid & 15, hs = tid >> 4;
  int w0 = wg * 4, h0 = hs * 4;
  float in[6][6];
#pragma unroll
  for (int ri = 0; ri < 6; ++ri) {
    int h = h0 - 1 + ri;
    if (h < 0 || h > 63) {
#pragma unroll
      for (int ci = 0; ci < 6; ++ci) in[ri][ci] = 0.f;
    } else {
      float4 cc = *(float4*)&p[h * 64 + w0];
      in[ri][1] = cc.x; in[ri][2] = cc.y; in[ri][3] = cc.z; in[ri][4] = cc.w;
      in[ri][0] = (w0 > 0) ? p[h * 64 + w0 - 1] : 0.f;
      in[ri][5] = (w0 < 60) ? p[h * 64 + w0 + 4] : 0.f;
    }
  }
#pragma unroll
  for (int r = 0; r < 4; ++r) {
    us4 oc;
#pragma unroll
    for (int q = 0; q < 4; ++q) {
      float acc = bv;
#pragma unroll
      for (int dh = 0; dh < 3; ++dh)
#pragma unroll
        for (int dq = 0; dq < 3; ++dq)
          acc += in[r + dh][q + dq] * wr[dh * 3 + dq];
      oc[q] = tobf(siluf(acc));
    }
    *(us4*)&o2[(long)bc * 4096 + (h0 + r) * 64 + w0] = oc;
  }
}

// K3: s[b,l,d] = sum_c o2[b,c,l]*w[c,d] (d<32). bf16 in/out. Folds prepW.
__global__ void k_fcin(const unsigned short* __restrict__ o2, const float* __restrict__ w,
                       unsigned short* __restrict__ sb,
                       const float* __restrict__ Win, unsigned short* __restrict__ WT) {
  __shared__ float xt[128][64];
  __shared__ float wt[128][32];
  int b = blockIdx.y, l0 = blockIdx.x * 64;
  int tid = threadIdx.x;
  int f4 = (tid & 15) * 4, r0 = tid >> 4;
#pragma unroll
  for (int st = 0; st < 8; ++st) {
    int r = r0 + st * 16;
    us4 v = *(const us4*)&o2[((long)b * 128 + r) * 4096 + l0 + f4];
#pragma unroll
    for (int j = 0; j < 4; ++j) xt[r][f4 + j] = frombf(v[j]);
  }
  int f4w = (tid & 7) * 4, rw = tid >> 3;
#pragma unroll
  for (int st = 0; st < 4; ++st) {
    int r = rw + st * 32;
    *(float4*)&wt[r][f4w] = *(const float4*)&w[r * 32 + f4w];
  }
  __syncthreads();
  int tx = tid & 15, ty = tid >> 4;
  int c0 = tx * 4, d0 = ty * 2;
  float acc[2][4] = {};
  for (int k = 0; k < 128; ++k) {
    float4 xv = *(float4*)&xt[k][c0];
    float2 wv = *(float2*)&wt[k][d0];
    float xa[4] = {xv.x, xv.y, xv.z, xv.w};
#pragma unroll
    for (int q = 0; q < 4; ++q) {
      acc[0][q] += wv.x * xa[q];
      acc[1][q] += wv.y * xa[q];
    }
  }
#pragma unroll
  for (int q = 0; q < 4; ++q) {
    long ob = ((long)b * 4096 + l0 + c0 + q) * 32 + d0;
    *(unsigned int*)&sb[ob] = pk2(acc[0][q], acc[1][q]);
  }
  // ---- folded prepW: WT[dir][n(272 padded)][k(32)], zeros n>=257 ----
  if (blockIdx.y == 0 && blockIdx.x < 2) {
    int dir = blockIdx.x;
    for (int idx = tid; idx < 272 * 32; idx += 256) {
      int n = idx >> 5, kk = idx & 31;
      float v = (n < 257) ? Win[dir * 32 * 257 + kk * 257 + n] : 0.f;
      WT[dir * 8704 + idx] = tobf(v);
    }
  }
}

// K4: in_proj (MFMA bf16, K=32) + causal conv1d + silu + dt softplus + cum
//     + fused chunk summary T[p][n] = sum_s f_s*X_s[p]*B_s[n] (MFMA bf16).
__global__ __launch_bounds__(256) void k_inprojconv(
    const unsigned short* __restrict__ sb, const unsigned short* __restrict__ WT,
    const float* __restrict__ conv_w, const float* __restrict__ conv_b,
    const float* __restrict__ dt_bias, const float* __restrict__ A_log,
    unsigned short* __restrict__ zT, unsigned short* __restrict__ xbca,
    float* __restrict__ dts, float* __restrict__ cum, float* __restrict__ Tg) {
  __shared__ unsigned short xbcT[192][82];   // [channel][t], pitch 82: conflict-free
  __shared__ float fXf[64][68];              // fp32 silu(X) for T's A-operand
  __shared__ float dtL[64];                  // raw dt MFMA outputs
  __shared__ float dtsS[64], cumSS[64], fL[64];
  int dir = blockIdx.z, b = blockIdx.y, l0 = blockIdx.x * 64;
  int tid = threadIdx.x, lane = tid & 63, mt = tid >> 6;
  int q = lane >> 4, i = lane & 15;
  long rowbase = (long)b * 4096 + l0;
  const unsigned short* W = WT + (long)dir * 8704;
  const short8 zfrag = {0, 0, 0, 0, 0, 0, 0, 0};

  if (mt == 0) {
    // ---- z columns (n 0..63) + dt column, l0-aligned rows ----
    short8 afr[4];
#pragma unroll
    for (int rt = 0; rt < 4; ++rt) {
      int l = l0 + 16 * rt + i;
      int lsrc = dir ? (4095 - l) : l;
      afr[rt] = *(const short8*)&sb[((long)b * 4096 + lsrc) * 32 + q * 8];
    }
#pragma unroll
    for (int ct = 0; ct < 4; ++ct) {
      int n = 16 * ct + i;
      short8 bfr = *(const short8*)&W[n * 32 + q * 8];
      unsigned short* zrow = zT + (((long)dir * 64 + n) * 8 + b) * 4096 + l0 + q * 4;
#pragma unroll
      for (int rt = 0; rt < 4; ++rt) {
        f32x4 d = {0.f, 0.f, 0.f, 0.f};
        d = __builtin_amdgcn_mfma_f32_16x16x32_bf16(afr[rt], bfr, d, 0, 0, 0);
        us4 pk;
        pk[0] = tobf(d[0]); pk[1] = tobf(d[1]);
        pk[2] = tobf(d[2]); pk[3] = tobf(d[3]);
        *(us4*)&zrow[16 * rt] = pk;
      }
    }
    {
      short8 bfr = *(const short8*)&W[(256 + i) * 32 + q * 8];
#pragma unroll
      for (int rt = 0; rt < 4; ++rt) {
        f32x4 d = {0.f, 0.f, 0.f, 0.f};
        d = __builtin_amdgcn_mfma_f32_16x16x32_bf16(afr[rt], bfr, d, 0, 0, 0);
        if (i == 0) {
#pragma unroll
          for (int r2 = 0; r2 < 4; ++r2) dtL[16 * rt + q * 4 + r2] = d[r2];
        }
      }
    }
  } else {
    // ---- xbc columns (n 64..255), rows with -3 conv halo ----
    short8 afr[5];
#pragma unroll
    for (int rt = 0; rt < 5; ++rt) {
      int l = l0 - 3 + 16 * rt + i;
      if (l >= 0 && l < 4096) {
        int lsrc = dir ? (4095 - l) : l;
        afr[rt] = *(const short8*)&sb[((long)b * 4096 + lsrc) * 32 + q * 8];
      } else {
        afr[rt] = zfrag;
      }
    }
#pragma unroll
    for (int cti = 0; cti < 4; ++cti) {
      int n = 16 * (mt * 4 + cti) + i;
      short8 bfr = *(const short8*)&W[n * 32 + q * 8];
      int cc = n - 64;
#pragma unroll
      for (int rt = 0; rt < 5; ++rt) {
        f32x4 d = {0.f, 0.f, 0.f, 0.f};
        d = __builtin_amdgcn_mfma_f32_16x16x32_bf16(afr[rt], bfr, d, 0, 0, 0);
        int rr0 = 16 * rt + q * 4;
        unsigned int p0 = (unsigned int)tobf(d[0]) | ((unsigned int)tobf(d[1]) << 16);
        unsigned int p1 = (unsigned int)tobf(d[2]) | ((unsigned int)tobf(d[3]) << 16);
        *(unsigned int*)&xbcT[cc][rr0] = p0;
        *(unsigned int*)&xbcT[cc][rr0 + 2] = p1;
      }
    }
  }
  __syncthreads();

  if (tid < 192) {
    int c = tid;
    float cw0 = conv_w[dir * 768 + c * 4 + 0];
    float cw1 = conv_w[dir * 768 + c * 4 + 1];
    float cw2 = conv_w[dir * 768 + c * 4 + 2];
    float cw3 = conv_w[dir * 768 + c * 4 + 3];
    float cb2 = conv_b[dir * 192 + c];
    unsigned short* xp = xbca + (long)dir * XSTRIDE_H;
    float win0 = 0.f, win1 = 0.f, win2 = 0.f, win3 = 0.f;
    for (int rp = 0; rp < 34; ++rp) {
      unsigned int pk = *(const unsigned int*)&xbcT[c][rp * 2];
      float a0 = frombf((unsigned short)(pk & 0xFFFFu));
      float a1 = frombf((unsigned short)(pk >> 16));
      int rr = rp * 2;
      win0 = win1; win1 = win2; win2 = win3; win3 = a0;
      if (rr >= 3 && rr <= 66) {
        float acc = cb2 + win0 * cw0 + win1 * cw1 + win2 * cw2 + win3 * cw3;
        float sv = siluf(acc);
        int t = rr - 3;
        xp[(rowbase + t) * 192 + c] = tobf(sv);
        if (c < 64) fXf[c][t] = sv;                        // fp32 X for T
        else if (c < 128) xbcT[c][t] = tobf(sv);           // bf16 B for T (trails reads by 3)
      }
      win0 = win1; win1 = win2; win2 = win3; win3 = a1;
      if (rr + 1 >= 3 && rr + 1 <= 66) {
        float acc = cb2 + win0 * cw0 + win1 * cw1 + win2 * cw2 + win3 * cw3;
        float sv = siluf(acc);
        int t = rr - 2;
        xp[(rowbase + t) * 192 + c] = tobf(sv);
        if (c < 64) fXf[c][t] = sv;
        else if (c < 128) xbcT[c][t] = tobf(sv);
      }
    }
  } else {
    int ln = tid - 192;
    float v = dtL[ln] + dt_bias[dir];
    float sp = (v > 20.f) ? v : log1pf(expf(v));
    dts[dir * 32768 + rowbase + ln] = sp;
    dtsS[ln] = sp;
    float cd = -expf(A_log[dir]) * sp;
#pragma unroll
    for (int off = 1; off < 64; off <<= 1) {
      float u = __shfl_up(cd, off);
      if (ln >= off) cd += u;
    }
    cum[dir * 32768 + rowbase + ln] = cd;
    cumSS[ln] = cd;
  }
  __syncthreads();

  if (tid < 64) fL[tid] = expf(cumSS[63] - cumSS[tid]) * dtsS[tid];
  __syncthreads();

  // scale phase: xbcT rows 0..63 <- tobf(fXf * fL)
  {
    int c = tid & 63, tb2 = (tid >> 6) * 16;
#pragma unroll
    for (int j = 0; j < 8; ++j) {
      int t = tb2 + 2 * j;
      float2 v = *(const float2*)&fXf[c][t];
      unsigned int pk = (unsigned int)tobf(v.x * fL[t]) |
                        ((unsigned int)tobf(v.y * fL[t + 1]) << 16);
      *(unsigned int*)&xbcT[c][t] = pk;
    }
  }
  __syncthreads();

  // MFMA-T: T[p][n] = sum_t fX[p][t] * B[n][t], K=64 (two K=32 MFMAs)
  {
    short8 a0 = ldfrag(&xbcT[mt * 16 + i][q * 8]);
    short8 a1 = ldfrag(&xbcT[mt * 16 + i][q * 8 + 32]);
    float* Tp = Tg + (long)dir * TSTRIDE + ((long)(b * 64 + blockIdx.x)) * 4096;
#pragma unroll
    for (int nt = 0; nt < 4; ++nt) {
      short8 b0 = ldfrag(&xbcT[64 + nt * 16 + i][q * 8]);
      short8 b1 = ldfrag(&xbcT[64 + nt * 16 + i][q * 8 + 32]);
      f32x4 d = {0.f, 0.f, 0.f, 0.f};
      d = __builtin_amdgcn_mfma_f32_16x16x32_bf16(a0, b0, d, 0, 0, 0);
      d = __builtin_amdgcn_mfma_f32_16x16x32_bf16(a1, b1, d, 0, 0, 0);
#pragma unroll
      for (int r2 = 0; r2 < 4; ++r2)
        Tp[(mt * 16 + q * 4 + r2) * 64 + nt * 16 + i] = d[r2];
    }
  }
}

// K7: inter-chunk state scan — pn-pairs, 16-deep prefetch, bf16 output.
__global__ void k_scan(const float* __restrict__ T, const float* __restrict__ cum,
                       unsigned short* __restrict__ Sprev) {
  __shared__ float E[64];
  int blk = blockIdx.x;            // 128 blocks
  int dirb = blk >> 3;             // dir*8 + b
  int dir = dirb >> 3, b = dirb & 7;
  int pn = (blk & 7) * 512 + threadIdx.x * 2;
  const float* cp = cum + dir * 32768 + b * 4096;
  if (threadIdx.x < 64) E[threadIdx.x] = expf(cp[threadIdx.x * 64 + 63]);
  __syncthreads();
  const float* Tp = T + (long)dir * TSTRIDE + (long)b * 262144 + pn;
  unsigned short* Sp = Sprev + (long)dir * TSTRIDE + (long)b * 262144 + pn;
  float s0 = 0.f, s1 = 0.f;
  float2 tb[16];
#pragma unroll
  for (int j = 0; j < 16; ++j) tb[j] = *(const float2*)&Tp[(long)j * 4096];
  for (int kc = 0; kc < 4; ++kc) {
    float2 tn[16];
    if (kc < 3) {
#pragma unroll
      for (int j = 0; j < 16; ++j)
        tn[j] = *(const float2*)&Tp[(long)(kc * 16 + 16 + j) * 4096];
    }
#pragma unroll
    for (int j = 0; j < 16; ++j) {
      int k = kc * 16 + j;
      *(unsigned int*)&Sp[(long)k * 4096] = pk2(s0, s1);
      s0 = fmaf(E[k], s0, tb[j].x);
      s1 = fmaf(E[k], s1, tb[j].y);
    }
    if (kc < 3) {
#pragma unroll
      for (int j = 0; j < 16; ++j) tb[j] = tn[j];
    }
  }
}

// K8: per-chunk Y + gate + RMSNorm + out-proj — MFMA bf16, vectorized staging.
__global__ __launch_bounds__(256) void k_chunkYout(
    const unsigned short* __restrict__ xbca, const float* __restrict__ dts,
    const float* __restrict__ cum, const unsigned short* __restrict__ Sprev,
    const float* __restrict__ Dp, const unsigned short* __restrict__ zT,
    const float* __restrict__ normw, const float* __restrict__ Wout,
    float* __restrict__ s2a, float* __restrict__ s2b) {
  __shared__ unsigned short Cb[64][72];
  __shared__ unsigned short Bop[64][68];
  __shared__ unsigned short Gb[64][72];
  __shared__ unsigned short WnT[32][66];
  __shared__ float cumS[64];
  int dir = blockIdx.y;
  int bk = blockIdx.x, b = bk >> 6, k = bk & 63;
  int tid = threadIdx.x, lane = tid & 63, mt = tid >> 6;
  int q = lane >> 4, i = lane & 15;
  const unsigned short* xp = xbca + (long)dir * XSTRIDE_H;
  const float* dtp = dts + dir * 32768;
  const float* cp = cum + dir * 32768;
  const unsigned short* Sp = Sprev + (long)dir * TSTRIDE;
  long base = (long)b * 4096 + (long)k * 64;

  {
    int c4 = (tid & 15) * 4, r0 = tid >> 4;
#pragma unroll
    for (int s = 0; s < 4; ++s) {
      int r = r0 + s * 16;
      float dtv = dtp[base + r];
      const unsigned short* rowp = &xp[(base + r) * 192 + 64];
      us4 bv = *(const us4*)&rowp[c4];
      us4 cv = *(const us4*)&rowp[64 + c4];
      us4 bo;
#pragma unroll
      for (int j = 0; j < 4; ++j) bo[j] = tobf(frombf(bv[j]) * dtv);
      *(us4*)&Bop[r][c4] = bo;
      *(us4*)&Cb[r][c4] = cv;
    }
  }
  for (int idx = tid; idx < 2048; idx += 256) {
    int p = idx >> 5, d = idx & 31;
    WnT[d][p] = tobf(normw[dir * 64 + p] * Wout[(long)dir * 2048 + p * 32 + d]);
  }
  if (tid < 64) cumS[tid] = cp[base + tid];
  __syncthreads();

  short8 a0 = *(const short8*)&Cb[mt * 16 + i][q * 8];
  short8 a1 = *(const short8*)&Cb[mt * 16 + i][q * 8 + 32];

#pragma unroll
  for (int lt = 0; lt < 4; ++lt) {
    short8 b0 = ldfrag(&Bop[lt * 16 + i][q * 8]);
    short8 b1 = ldfrag(&Bop[lt * 16 + i][q * 8 + 32]);
    f32x4 d = {0.f, 0.f, 0.f, 0.f};
    d = __builtin_amdgcn_mfma_f32_16x16x32_bf16(a0, b0, d, 0, 0, 0);
    d = __builtin_amdgcn_mfma_f32_16x16x32_bf16(a1, b1, d, 0, 0, 0);
#pragma unroll
    for (int r2 = 0; r2 < 4; ++r2) {
      int t = mt * 16 + q * 4 + r2;
      int l = lt * 16 + i;
      float g = (l <= t) ? d[r2] * expf(cumS[t] - cumS[l]) : 0.f;
      Gb[t][l] = tobf(g);
    }
  }
  __syncthreads();

  {
    int c4 = (tid & 15) * 4, r0 = tid >> 4;
#pragma unroll
    for (int s = 0; s < 4; ++s) {
      int r = r0 + s * 16;
      us4 sv = *(const us4*)&Sp[(long)bk * 4096 + r * 64 + c4];
      *(us4*)&Bop[r][c4] = sv;
    }
  }
  __syncthreads();

  f32x4 dint[4];
#pragma unroll
  for (int lt = 0; lt < 4; ++lt) {
    short8 b0 = ldfrag(&Bop[lt * 16 + i][q * 8]);
    short8 b1 = ldfrag(&Bop[lt * 16 + i][q * 8 + 32]);
    f32x4 d = {0.f, 0.f, 0.f, 0.f};
    d = __builtin_amdgcn_mfma_f32_16x16x32_bf16(a0, b0, d, 0, 0, 0);
    d = __builtin_amdgcn_mfma_f32_16x16x32_bf16(a1, b1, d, 0, 0, 0);
    dint[lt] = d;
  }
  __syncthreads();

  // Repack X transposed into Bop: Bop[p][t] = X[row t][channel p]
#pragma unroll
  for (int j = 0; j < 8; ++j) {
    int s = mt * 16 + 2 * j;
    unsigned int pk = (unsigned int)xp[(base + s) * 192 + lane] |
                      ((unsigned int)xp[(base + s + 1) * 192 + lane] << 16);
    *(unsigned int*)&Bop[lane][s] = pk;
  }
  __syncthreads();

  short8 g0 = *(const short8*)&Gb[mt * 16 + i][q * 8];
  short8 g1 = *(const short8*)&Gb[mt * 16 + i][q * 8 + 32];
  float Dv = Dp[dir];
  float et4[4];
#pragma unroll
  for (int r2 = 0; r2 < 4; ++r2) et4[r2] = expf(cumS[mt * 16 + q * 4 + r2]);
  float yv[4][4];
  float rowss[4] = {0.f, 0.f, 0.f, 0.f};
#pragma unroll
  for (int lt = 0; lt < 4; ++lt) {
    short8 b0 = ldfrag(&Bop[lt * 16 + i][q * 8]);
    short8 b1 = ldfrag(&Bop[lt * 16 + i][q * 8 + 32]);
    f32x4 d = {0.f, 0.f, 0.f, 0.f};
    d = __builtin_amdgcn_mfma_f32_16x16x32_bf16(g0, b0, d, 0, 0, 0);
    d = __builtin_amdgcn_mfma_f32_16x16x32_bf16(g1, b1, d, 0, 0, 0);
    us4 zq = *(const us4*)&zT[(((long)dir * 64 + lt * 16 + i) * 8 + b) * 4096 +
                              (long)k * 64 + mt * 16 + q * 4];
    unsigned int xpk0 = *(const unsigned int*)&Bop[lt * 16 + i][mt * 16 + q * 4];
    unsigned int xpk1 = *(const unsigned int*)&Bop[lt * 16 + i][mt * 16 + q * 4 + 2];
    float xvr[4];
    xvr[0] = frombf((unsigned short)(xpk0 & 0xFFFFu));
    xvr[1] = frombf((unsigned short)(xpk0 >> 16));
    xvr[2] = frombf((unsigned short)(xpk1 & 0xFFFFu));
    xvr[3] = frombf((unsigned short)(xpk1 >> 16));
#pragma unroll
    for (int r2 = 0; r2 < 4; ++r2) {
      float y = d[r2] + et4[r2] * dint[lt][r2] + Dv * xvr[r2];
      float zv = frombf(zq[r2]);
      float v = y * siluf(zv);
      yv[lt][r2] = v;
      rowss[r2] += v * v;
    }
  }
#pragma unroll
  for (int m = 1; m < 16; m <<= 1) {
#pragma unroll
    for (int r2 = 0; r2 < 4; ++r2) rowss[r2] += __shfl_xor(rowss[r2], m);
  }
  float rscv[4];
#pragma unroll
  for (int r2 = 0; r2 < 4; ++r2)
    rscv[r2] = rsqrtf(rowss[r2] * (1.0f / 64.0f) + 1e-5f);
#pragma unroll
  for (int lt = 0; lt < 4; ++lt)
#pragma unroll
    for (int r2 = 0; r2 < 4; ++r2) {
      int t = mt * 16 + q * 4 + r2;
      int p = lt * 16 + i;
      Gb[t][p] = tobf(yv[lt][r2] * rscv[r2]);
    }
  __syncthreads();

  short8 y0 = *(const short8*)&Gb[mt * 16 + i][q * 8];
  short8 y1 = *(const short8*)&Gb[mt * 16 + i][q * 8 + 32];
  float* s2x = dir ? s2b : s2a;
#pragma unroll
  for (int dt = 0; dt < 2; ++dt) {
    short8 b0 = ldfrag(&WnT[dt * 16 + i][q * 8]);
    short8 b1 = ldfrag(&WnT[dt * 16 + i][q * 8 + 32]);
    f32x4 d = {0.f, 0.f, 0.f, 0.f};
    d = __builtin_amdgcn_mfma_f32_16x16x32_bf16(y0, b0, d, 0, 0, 0);
    d = __builtin_amdgcn_mfma_f32_16x16x32_bf16(y1, b1, d, 0, 0, 0);
#pragma unroll
    for (int r2 = 0; r2 < 4; ++r2) {
      int tl = mt * 16 + q * 4 + r2;
      int l = k * 64 + tl;
      int lout = dir ? (4095 - l) : l;
      int dd = dt * 16 + i;
      s2x[((long)b * 4096 + lout) * 32 + dd] = d[r2];
    }
  }
}

// K10: o3 = (s2a+s2b)@W — GEMM (bf16 out) + BN partials to scratch (no atomics).
__global__ void k_fcout(const float* __restrict__ s2a, const float* __restrict__ s2b,
                        const float* __restrict__ w, unsigned short* __restrict__ o3,
                        float* __restrict__ part) {
  __shared__ float st[32][68];
  __shared__ float wt[32][64];
  int b = blockIdx.y, l0 = blockIdx.x * 64, cb = blockIdx.z * 64;
  int tid = threadIdx.x;
  {
    int d = tid & 31, l = tid >> 5;
    for (int si = 0; si < 8; ++si) {
      int ll = l + si * 8;
      long o = ((long)b * 4096 + l0 + ll) * 32 + d;
      st[d][ll] = s2a[o] + s2b[o];
    }
    int f4 = (tid & 15) * 4, r = tid >> 4;
    for (int si = 0; si < 2; ++si) {
      int rr = r + si * 16;
      *(float4*)&wt[rr][f4] = *(const float4*)&w[rr * 128 + cb + f4];
    }
  }
  __syncthreads();
  int tx = tid & 15, ty = tid >> 4;
  int c0 = tx * 4, t0 = ty * 4;
  float acc[4][4] = {};
  for (int k = 0; k < 32; ++k) {
    float4 xv = *(float4*)&st[k][c0];
    float4 wv = *(float4*)&wt[k][t0];
    float xa[4] = {xv.x, xv.y, xv.z, xv.w};
    float wa[4] = {wv.x, wv.y, wv.z, wv.w};
#pragma unroll
    for (int a = 0; a < 4; ++a)
#pragma unroll
      for (int q = 0; q < 4; ++q) acc[a][q] += wa[a] * xa[q];
  }
#pragma unroll
  for (int a = 0; a < 4; ++a) {
    us4 pk;
#pragma unroll
    for (int q = 0; q < 4; ++q) pk[q] = tobf(acc[a][q]);
    *(us4*)&o3[((long)b * 128 + cb + t0 + a) * 4096 + l0 + c0] = pk;
  }
  // ---- BN partial sums: reduce over the 16 l-lanes, store per-block partials ----
  float ssum[4], sqq[4];
#pragma unroll
  for (int a = 0; a < 4; ++a) {
    ssum[a] = acc[a][0] + acc[a][1] + acc[a][2] + acc[a][3];
    sqq[a] = acc[a][0] * acc[a][0] + acc[a][1] * acc[a][1] +
             acc[a][2] * acc[a][2] + acc[a][3] * acc[a][3];
  }
#pragma unroll
  for (int m = 1; m < 16; m <<= 1) {
#pragma unroll
    for (int a = 0; a < 4; ++a) {
      ssum[a] += __shfl_xor(ssum[a], m);
      sqq[a] += __shfl_xor(sqq[a], m);
    }
  }
  if (tx == 0) {
    int idx = b * 64 + blockIdx.x;   // 512 slots per channel
#pragma unroll
    for (int a = 0; a < 4; ++a) {
      int ch = cb + t0 + a;
      part[(long)ch * 512 + idx] = ssum[a];
      part[65536 + (long)ch * 512 + idx] = sqq[a];
    }
  }
}

// K11: reduce BN partials (128 blocks = 1 per channel). No atomics anywhere.
__global__ void k_bnred(const float* __restrict__ part, float* __restrict__ stats) {
  int ch = blockIdx.x, tid = threadIdx.x;
  float s = part[(long)ch * 512 + tid] + part[(long)ch * 512 + 256 + tid];
  float q = part[65536 + (long)ch * 512 + tid] +
            part[65536 + (long)ch * 512 + 256 + tid];
  for (int off = 32; off; off >>= 1) {
    s += __shfl_down(s, off);
    q += __shfl_down(q, off);
  }
  __shared__ float rs[4], rq[4];
  if ((tid & 63) == 0) { rs[tid >> 6] = s; rq[tid >> 6] = q; }
  __syncthreads();
  if (tid == 0) {
    stats[ch] = rs[0] + rs[1] + rs[2] + rs[3];
    stats[128 + ch] = rq[0] + rq[1] + rq[2] + rq[3];
  }
}

// K12: BN + conv4 + sigmoid + gated residual — MFMA bf16 (BN folded in staging).
__global__ __launch_bounds__(256) void k_final(const unsigned short* __restrict__ o3,
                                               const float* __restrict__ stats,
                                               const float* __restrict__ bng,
                                               const float* __restrict__ bnb,
                                               const float* __restrict__ w,
                                               const float* __restrict__ bias,
                                               const float* __restrict__ x,
                                               float* __restrict__ out) {
  __shared__ unsigned short wT[64][140];
  __shared__ unsigned short aT[64][140];
  __shared__ float sc[128], sh[128];
  int b = blockIdx.y, l0 = blockIdx.x * 64, cb = blockIdx.z * 64;
  int tid = threadIdx.x, lane = tid & 63, mt = tid >> 6;
  int q = lane >> 4, i = lane & 15;
  if (tid < 128) {
    float mu = stats[tid] * (1.0f / 32768.0f);
    float var = stats[128 + tid] * (1.0f / 32768.0f) - mu * mu;
    float r = rsqrtf(var + 1e-5f);
    sc[tid] = r * bng[tid];
    sh[tid] = bnb[tid] - mu * r * bng[tid];
  }
  __syncthreads();
  int c4 = (tid & 15) * 4, k0 = (tid >> 4) * 2;
#pragma unroll
  for (int s = 0; s < 4; ++s) {
    int k = k0 + s * 32;
    float4 w0 = *(const float4*)&w[k * 128 + cb + c4];
    float4 w1 = *(const float4*)&w[(k + 1) * 128 + cb + c4];
    *(unsigned int*)&wT[c4 + 0][k] = pk2(w0.x, w1.x);
    *(unsigned int*)&wT[c4 + 1][k] = pk2(w0.y, w1.y);
    *(unsigned int*)&wT[c4 + 2][k] = pk2(w0.z, w1.z);
    *(unsigned int*)&wT[c4 + 3][k] = pk2(w0.w, w1.w);
    us4 a0 = *(const us4*)&o3[((long)b * 128 + k) * 4096 + l0 + c4];
    us4 a1 = *(const us4*)&o3[((long)b * 128 + k + 1) * 4096 + l0 + c4];
    float sc0 = sc[k], sh0 = sh[k], sc1 = sc[k + 1], sh1 = sh[k + 1];
#pragma unroll
    for (int j = 0; j < 4; ++j) {
      *(unsigned int*)&aT[c4 + j][k] =
          pk2(fmaf(frombf(a0[j]), sc0, sh0), fmaf(frombf(a1[j]), sc1, sh1));
    }
  }
  __syncthreads();
  short8 af[4];
#pragma unroll
  for (int kk = 0; kk < 4; ++kk)
    af[kk] = ldfrag(&wT[mt * 16 + i][q * 8 + 32 * kk]);
  float bv[4];
#pragma unroll
  for (int r2 = 0; r2 < 4; ++r2) bv[r2] = bias[cb + 16 * mt + q * 4 + r2];
#pragma unroll
  for (int nt = 0; nt < 4; ++nt) {
    f32x4 d = {0.f, 0.f, 0.f, 0.f};
#pragma unroll
    for (int kk = 0; kk < 4; ++kk) {
      short8 bfr = ldfrag(&aT[nt * 16 + i][q * 8 + 32 * kk]);
      d = __builtin_amdgcn_mfma_f32_16x16x32_bf16(af[kk], bfr, d, 0, 0, 0);
    }
#pragma unroll
    for (int r2 = 0; r2 < 4; ++r2) {
      int c = 16 * mt + q * 4 + r2;
      long xi = ((long)b * 128 + cb + c) * 4096 + l0 + nt * 16 + i;
      float g = 1.0f / (1.0f + expf(-(d[r2] + bv[r2])));
      out[xi] = x[xi] * (1.0f + g);
    }
  }
}

extern "C" void kernel_launch(void* const* d_in, const int* in_sizes, int n_in,
                              void* d_out, int out_size, void* d_ws, size_t ws_size,
                              hipStream_t stream) {
  const float* x          = (const float*)d_in[0];
  const float* lin1_w     = (const float*)d_in[1];
  const float* lin1_b     = (const float*)d_in[2];
  const float* dw_w       = (const float*)d_in[3];
  const float* dw_b       = (const float*)d_in[4];
  const float* fc_in_w    = (const float*)d_in[5];
  const float* mam_in_w   = (const float*)d_in[6];
  const float* mam_conv_w = (const float*)d_in[7];
  const float* mam_conv_b = (const float*)d_in[8];
  const float* mam_dt_bias= (const float*)d_in[9];
  const float* mam_A_log  = (const float*)d_in[10];
  const float* mam_D      = (const float*)d_in[11];
  const float* mam_norm_w = (const float*)d_in[12];
  const float* mam_out_w  = (const float*)d_in[13];
  const float* fc_out_w   = (const float*)d_in[14];
  const float* bn_g       = (const float*)d_in[15];
  const float* bn_b       = (const float*)d_in[16];
  const float* conv4_w    = (const float*)d_in[17];
  const float* conv4_b    = (const float*)d_in[18];
  float* out = (float*)d_out;
  float* ws  = (float*)d_ws;

  unsigned short* o1h  = (unsigned short*)(ws + OFF_O1);
  unsigned short* o2h  = (unsigned short*)(ws + OFF_O2);
  unsigned short* sbuf = (unsigned short*)(ws + OFF_S);
  unsigned short* zTb  = (unsigned short*)(ws + OFF_Z);
  unsigned short* WTb  = (unsigned short*)(ws + OFF_WT);
  unsigned short* xbca = (unsigned short*)(ws + OFF_XBCA);
  float* dts  = ws + OFF_DTS;
  float* cum  = ws + OFF_CUM;
  float* Tbuf = ws + OFF_T;
  unsigned short* Sprev = (unsigned short*)(ws + OFF_SPREV);
  float* s2a  = ws + OFF_S2A;
  float* s2b  = ws + OFF_S2B;
  float* bnst = ws + OFF_BN;
  unsigned short* o3h = (unsigned short*)(ws + OFF_O3);
  float* part = ws + OFF_T;   // Tbuf dead after k_scan; reuse for BN partials

  k_lin1<<<dim3(64, 8, 2), 256, 0, stream>>>(x, lin1_w, lin1_b, o1h);
  k_dw<<<1024, 256, 0, stream>>>(o1h, dw_w, dw_b, o2h);
  k_fcin<<<dim3(64, 8), 256, 0, stream>>>(o2h, fc_in_w, sbuf, mam_in_w, WTb);
  k_inprojconv<<<dim3(64, 8, 2), 256, 0, stream>>>(sbuf, WTb, mam_conv_w, mam_conv_b,
                                                   mam_dt_bias, mam_A_log,
                                                   zTb, xbca, dts, cum, Tbuf);
  k_scan<<<128, 256, 0, stream>>>(Tbuf, cum, Sprev);
  k_chunkYout<<<dim3(512, 2), 256, 0, stream>>>(xbca, dts, cum, Sprev, mam_D, zTb,
                                                mam_norm_w, mam_out_w, s2a, s2b);
  k_fcout<<<dim3(64, 8, 2), 256, 0, stream>>>(s2a, s2b, fc_out_w, o3h, part);
  k_bnred<<<128, 256, 0, stream>>>(part, bnst);
  k_final<<<dim3(64, 8, 2), 256, 0, stream>>>(o3h, bnst, bn_g, bn_b, conv4_w, conv4_b, x, out);
}